// Round 4
// baseline (559.166 us; speedup 1.0000x reference)
//
#include <hip/hip_runtime.h>
#include <math.h>

#define N 4096
#define ROUNDS 12           // components at least halve per round: 4096 -> 1 guaranteed
#define INFKEY 0xFFFFFFFFFFFFFFFFULL
#define LCAP 48             // candidate-list capacity per row

typedef unsigned long long u64;
typedef unsigned short u16;
typedef unsigned char u8;

// ---- workspace layout (bytes) ----
#define WS_PARENT(ws) ((int*)((char*)(ws) + 0))          // int[2N]    32 KB
#define WS_RCNT(ws)   ((int*)((char*)(ws) + 32768))      // int[2N]    32 KB
#define WS_RTHR(ws)   ((float*)((char*)(ws) + 65536))    // float[2N]  32 KB
#define WS_EDGES(ws)  ((int2*)((char*)(ws) + 98304))     // int2[2N]   64 KB
#define WS_LISTS(ws)  ((u64*)((char*)(ws) + 163840))     // u64[2N*LCAP] 3 MB

// cand key: (float_bits(w) << 24) | (u << 12) | v    (56 bits)
// list entry: (float_bits(w) << 12) | j              (44 bits)
// distances >= 0 -> float bit pattern order-preserving; weights unique (fp32 Gaussian).

// One wave per row, one full-matrix streaming pass. Per-row threshold
// T = min + 0.25*(mean-min); entries < T compacted via count -> 64-lane
// prefix scan -> scatter (list order irrelevant: consumers only take mins).
__global__ __launch_bounds__(1024) void build_kernel(const float* __restrict__ D1,
                                                     const float* __restrict__ D2,
                                                     int* __restrict__ rowcount,
                                                     float* __restrict__ rthresh,
                                                     u64* __restrict__ lists) {
    const int gb = blockIdx.x;   // 512 blocks: 256 per matrix
    const int tid = threadIdx.x;
    const int m = gb >> 8;
    const int wid = tid >> 6, lane = tid & 63;
    const int row = (gb & 255) * 16 + wid;
    const float* __restrict__ Drow = (m ? D2 : D1) + (size_t)row * N;
    const float INF = __builtin_inff();

    // full row in registers: 16 independent float4 loads (high MLP)
    float4 v[16];
#pragma unroll
    for (int it = 0; it < 16; ++it)
        v[it] = *(const float4*)(Drow + it * 256 + lane * 4);

    float mn = INF, sm = 0.f;
#pragma unroll
    for (int it = 0; it < 16; ++it) {
        float a = v[it].x, b = v[it].y, c = v[it].z, d = v[it].w;
        mn = fminf(mn, a > 0.f ? a : INF);   // excludes exact-zero diagonal
        mn = fminf(mn, b > 0.f ? b : INF);
        mn = fminf(mn, c > 0.f ? c : INF);
        mn = fminf(mn, d > 0.f ? d : INF);
        sm += a + b + c + d;                 // self adds 0, harmless
    }
#pragma unroll
    for (int off = 32; off > 0; off >>= 1) {
        mn = fminf(mn, __shfl_xor(mn, off, 64));
        sm += __shfl_xor(sm, off, 64);
    }
    const float mean = sm * (1.f / 4095.f);
    const float T = mn + 0.25f * (mean - mn);

    // per-lane predicate count
    int mycnt = 0;
#pragma unroll
    for (int it = 0; it < 16; ++it) {
        mycnt += (v[it].x > 0.f && v[it].x < T);
        mycnt += (v[it].y > 0.f && v[it].y < T);
        mycnt += (v[it].z > 0.f && v[it].z < T);
        mycnt += (v[it].w > 0.f && v[it].w < T);
    }
    // 64-lane inclusive scan
    int incl = mycnt;
#pragma unroll
    for (int d = 1; d < 64; d <<= 1) {
        int o = __shfl_up(incl, d, 64);
        if (lane >= d) incl += o;
    }
    const int total = __shfl(incl, 63, 64);
    int pos = incl - mycnt;

    u64* lp = lists + (size_t)(m * N + row) * LCAP;
#pragma unroll
    for (int it = 0; it < 16; ++it) {
        float e4[4] = {v[it].x, v[it].y, v[it].z, v[it].w};
#pragma unroll
        for (int s = 0; s < 4; ++s) {
            float x = e4[s];
            if (x > 0.f && x < T) {
                if (pos < LCAP)
                    lp[pos] = ((u64)__float_as_uint(x) << 12) | (unsigned)(it * 256 + lane * 4 + s);
                ++pos;
            }
        }
    }
    if (lane == 0) {
        rowcount[m * N + row] = total;   // > LCAP marks overflow
        rthresh[m * N + row] = T;
    }
}

// One workgroup per matrix: ALL Boruvka rounds + rooting BFS in a single
// dispatch. comp/cand in LDS (u64 LDS atomicMin), rescan rows compacted into
// an LDS worklist, edges appended to global scratch, then BFS-oriented.
__global__ __launch_bounds__(1024) void solve_kernel(const float* __restrict__ D1,
                                                     const float* __restrict__ D2,
                                                     const int* __restrict__ rcnt,
                                                     const float* __restrict__ rthr,
                                                     const u64* __restrict__ lists,
                                                     int2* __restrict__ edges_g,
                                                     int* __restrict__ parent_g) {
    const int m = blockIdx.x;
    const int tid = threadIdx.x;
    const int wid = tid >> 6, lane = tid & 63;
    const float* __restrict__ D = m ? D2 : D1;
    const int* __restrict__ grc = rcnt + m * N;
    const float* __restrict__ gth = rthr + m * N;
    const u64* __restrict__ gls = lists + (size_t)m * N * LCAP;
    int2* __restrict__ ged = edges_g + (size_t)m * N;
    int* __restrict__ gpar = parent_g + m * N;

    __shared__ __align__(16) char SM[57344];   // 56 KB < 64 KB/WG limit
    int* scomp = (int*)SM;                     // 16 KB @0
    u64* scand = (u64*)(SM + 16384);           // 32 KB @16K
    u16* sresc = (u16*)(SM + 49152);           // 8 KB  @48K (aliased: slink in hook)
    __shared__ int sdone, secnt, snres, scnt, schanged;

    for (int i = tid; i < N; i += 1024) { scomp[i] = i; scand[i] = INFKEY; }
    if (tid == 0) { sdone = 0; secnt = 0; }
    __syncthreads();

    for (int round = 0; round < ROUNDS; ++round) {
        if (sdone) break;                       // uniform (set before last barrier)
        if (tid == 0) snres = 0;
        __syncthreads();

        // ---- phase 1: exact row cross-min from candidate list ----
        for (int row = tid; row < N; row += 1024) {
            int c = scomp[row];
            int cnt = grc[row];
            int flag = 0;
            if (cnt > LCAP) {
                flag = 2;                       // overflow: bound invalid, must rescan
            } else {
                u64 best = INFKEY;
                const u64* lp = gls + (size_t)row * LCAP;
                for (int k = 0; k < cnt; ++k) {
                    u64 e = lp[k];
                    int j = (int)(e & 0xFFF);
                    if (scomp[j] != c && e < best) best = e;
                }
                if (best != INFKEY)
                    atomicMin(&scand[c], ((best >> 12) << 24) | ((u64)row << 12) | (best & 0xFFF));
                else
                    flag = 1;                   // exhausted: true cross-min >= T_row
            }
            if (flag) {
                int i = atomicAdd(&snres, 1);
                sresc[i] = (u16)(row | (flag == 2 ? 0x2000 : 0x1000));
            }
        }
        __syncthreads();

        // ---- phase 2: filter exhausted rows that cannot beat comp candidate ----
        // scand is quiescent here (barrier), so reads are tear-free. Skip is safe:
        // cand only decreases, rowmin >= T >= current w >= final w.
        for (int i = tid; i < snres; i += 1024) {
            u16 e = sresc[i];
            if (e & 0x1000) {
                int row = e & 0xFFF;
                int c = scomp[row];
                u64 cc = scand[c];
                float w = (cc == INFKEY) ? __builtin_inff()
                                         : __uint_as_float((unsigned)(cc >> 24));
                if (!(gth[row] < w)) sresc[i] = 0xFFFF;
            }
        }
        __syncthreads();

        // ---- phase 3: full 16KB row rescan, one wave per surviving entry ----
        {
            int nres = snres;
            for (int i = wid; i < nres; i += 16) {
                u16 e = sresc[i];               // wave-uniform broadcast read
                if (e == 0xFFFF) continue;
                int row = (int)(e & 0xFFF);
                int c = scomp[row];
                const float* Drow = D + (size_t)row * N;
                u64 best = INFKEY;
                for (int j0 = lane * 4; j0 < N; j0 += 256) {
                    float4 d = *(const float4*)(Drow + j0);
                    int4 cj = *(const int4*)(scomp + j0);
                    if (cj.x != c) { u64 k = ((u64)__float_as_uint(d.x) << 12) | (unsigned)(j0 + 0); if (k < best) best = k; }
                    if (cj.y != c) { u64 k = ((u64)__float_as_uint(d.y) << 12) | (unsigned)(j0 + 1); if (k < best) best = k; }
                    if (cj.z != c) { u64 k = ((u64)__float_as_uint(d.z) << 12) | (unsigned)(j0 + 2); if (k < best) best = k; }
                    if (cj.w != c) { u64 k = ((u64)__float_as_uint(d.w) << 12) | (unsigned)(j0 + 3); if (k < best) best = k; }
                }
#pragma unroll
                for (int off = 32; off > 0; off >>= 1) {
                    u64 o = __shfl_xor(best, off, 64);
                    if (o < best) best = o;
                }
                if (lane == 0 && best != INFKEY)
                    atomicMin(&scand[c], ((best >> 12) << 24) | ((u64)row << 12) | (best & 0xFFF));
            }
        }
        __syncthreads();

        // ---- phase 4: hook roots, record edges, compress, completion check ----
        u16* slink = sresc;  // rescan list dead; reuse region
        for (int c = tid; c < N; c += 1024) {
            int l = scomp[c];
            if (l == c) {
                u64 k = scand[c];
                if (k != INFKEY) {
                    int v = (int)(k & 0xFFF);
                    int u = (int)((k >> 12) & 0xFFF);
                    int t = scomp[v];
                    u64 tk = scand[t];
                    int mutual = 0;
                    if (tk != INFKEY) {
                        int tv = (int)(tk & 0xFFF);
                        mutual = (scomp[tv] == c);
                    }
                    if (mutual) {
                        if (c < t) { int idx = atomicAdd(&secnt, 1); ged[idx] = make_int2(u, v); }
                        else l = t;
                    } else {
                        int idx = atomicAdd(&secnt, 1); ged[idx] = make_int2(u, v); l = t;
                    }
                }
            }
            slink[c] = (u16)l;
        }
        __syncthreads();
        for (int c = tid; c < N; c += 1024) scomp[c] = slink[c];
        __syncthreads();
        for (int it = 0; it < 12; ++it) {   // in-place pointer jumping (race-tolerant)
            for (int c = tid; c < N; c += 1024) scomp[c] = scomp[scomp[c]];
            __syncthreads();
        }
        if (tid == 0) scnt = 0;
        __syncthreads();
        int local = 0;
        for (int c = tid; c < N; c += 1024) local += (scomp[c] == c) ? 1 : 0;
        atomicAdd(&scnt, local);
        __syncthreads();
        if (tid == 0 && scnt == 1) sdone = 1;
        for (int c = tid; c < N; c += 1024) scand[c] = INFKEY;
        __syncthreads();
    }

    // ---- rooting: orient edges toward node 0 (level-sync BFS, all LDS) ----
    const int ec = secnt;                      // == N-1
    int* sp = (int*)SM;                        // reuse scomp region (16 KB)
    int2* se = (int2*)(SM + 16384);            // reuse scand region (32 KB)
    u8* kprev = (u8*)(SM + 49152);             // 4 KB
    u8* kcur = (u8*)(SM + 53248);              // 4 KB
    for (int i = tid; i < ec; i += 1024) se[i] = ged[i];  // own block's writes, post-barrier
    for (int i = tid; i < N; i += 1024) { sp[i] = 0; kprev[i] = 0; kcur[i] = 0; }
    __syncthreads();
    if (tid == 0) { kprev[0] = 1; kcur[0] = 1; }
    __syncthreads();
    for (int pass = 0; pass < N; ++pass) {
        if (tid == 0) schanged = 0;
        __syncthreads();
        for (int e = tid; e < ec; e += 1024) {
            int2 uv = se[e];
            u8 ku = kprev[uv.x], kv = kprev[uv.y];
            if (ku && !kv) { sp[uv.y] = uv.x; kcur[uv.y] = 1; schanged = 1; }
            else if (kv && !ku) { sp[uv.x] = uv.y; kcur[uv.x] = 1; schanged = 1; }
        }
        __syncthreads();
        int go = schanged;
        __syncthreads();
        if (!go) break;
        for (int i = tid; i < N; i += 1024) kprev[i] = kcur[i];
        __syncthreads();
    }
    for (int i = tid; i < N; i += 1024) gpar[i] = sp[i];
}

__global__ __launch_bounds__(1024) void finalize_kernel(const float* __restrict__ D1,
                                                        const float* __restrict__ D2,
                                                        const int* __restrict__ parent,
                                                        float* __restrict__ out) {
    __shared__ float rs12[16], rs21[16];
    __shared__ int rm[16];
    const int tid = threadIdx.x;
    const int* p1 = parent;
    const int* p2 = parent + N;

    float s12 = 0.f, s21 = 0.f;
    int mcnt = 0;
    for (int c = 1 + tid; c < N; c += 1024) {
        int a = p1[c];
        int b = p2[c];
        float e1 = D1[(size_t)a * N + c] - D2[(size_t)a * N + c];
        float e2 = D2[(size_t)b * N + c] - D1[(size_t)b * N + c];
        s12 += e1 * e1;
        s21 += e2 * e2;
        mcnt += (a == b) ? 1 : 0;
    }
#pragma unroll
    for (int off = 32; off > 0; off >>= 1) {
        s12 += __shfl_xor(s12, off, 64);
        s21 += __shfl_xor(s21, off, 64);
        mcnt += __shfl_xor(mcnt, off, 64);
    }
    const int wid = tid >> 6, lane = tid & 63;
    if (lane == 0) { rs12[wid] = s12; rs21[wid] = s21; rm[wid] = mcnt; }
    __syncthreads();
    if (tid == 0) {
        float a = 0.f, b = 0.f;
        int mm = 0;
#pragma unroll
        for (int w = 0; w < 16; ++w) { a += rs12[w]; b += rs21[w]; mm += rm[w]; }
        float d12 = sqrtf(a);
        float d21 = sqrtf(b);
        out[0] = d12 + d21;
        out[1] = d12;
        out[2] = d21;
        out[3] = (float)mm;
    }
}

extern "C" void kernel_launch(void* const* d_in, const int* in_sizes, int n_in,
                              void* d_out, int out_size, void* d_ws, size_t ws_size,
                              hipStream_t stream) {
    const float* D1 = (const float*)d_in[0];
    const float* D2 = (const float*)d_in[1];

    int* parent = WS_PARENT(d_ws);
    int* rcnt = WS_RCNT(d_ws);
    float* rthr = WS_RTHR(d_ws);
    int2* edges = WS_EDGES(d_ws);
    u64* lists = WS_LISTS(d_ws);

    build_kernel<<<512, 1024, 0, stream>>>(D1, D2, rcnt, rthr, lists);
    solve_kernel<<<2, 1024, 0, stream>>>(D1, D2, rcnt, rthr, lists, edges, parent);
    finalize_kernel<<<1, 1024, 0, stream>>>(D1, D2, parent, (float*)d_out);
}

// Round 5
// 452.480 us; speedup vs baseline: 1.2358x; 1.2358x over previous
//
#include <hip/hip_runtime.h>
#include <math.h>

#define N 4096
#define ROUNDS 12           // components at least halve per round: 4096 -> 1 guaranteed
#define INFKEY 0xFFFFFFFFFFFFFFFFULL
#define LCAP 48             // candidate-list capacity per row
#define EC (N - 1)          // MST edge count
#define M2 (2 * EC)         // directed edges (8190)

typedef unsigned long long u64;
typedef unsigned int u32;
typedef unsigned short u16;

// ---- workspace layout (bytes) ----
#define WS_PARENT(ws) ((int*)((char*)(ws) + 0))          // int[2N]    32 KB
#define WS_RCNT(ws)   ((int*)((char*)(ws) + 32768))      // int[2N]    32 KB
#define WS_RTHR(ws)   ((float*)((char*)(ws) + 65536))    // float[2N]  32 KB
#define WS_EDGES(ws)  ((int2*)((char*)(ws) + 98304))     // int2[2N]   64 KB
#define WS_LISTS(ws)  ((u64*)((char*)(ws) + 163840))     // u64[2N*LCAP] 3 MB, column-major per matrix

// cand key: (float_bits(w) << 24) | (u << 12) | v    (56 bits)
// list entry: (float_bits(w) << 12) | j              (44 bits)
// distances >= 0 -> float bit pattern order-preserving; weights unique (fp32 Gaussian).

// One wave per row, one full-matrix streaming pass. Per-row threshold
// T = min + 0.25*(mean-min); entries < T compacted (count -> lane scan ->
// scatter) into COLUMN-MAJOR lists: entry (row,k) at lists[mbase + k*N + row],
// so the solver's thread-per-row reads are fully coalesced.
__global__ __launch_bounds__(1024) void build_kernel(const float* __restrict__ D1,
                                                     const float* __restrict__ D2,
                                                     int* __restrict__ rowcount,
                                                     float* __restrict__ rthresh,
                                                     u64* __restrict__ lists) {
    const int gb = blockIdx.x;   // 512 blocks: 256 per matrix
    const int tid = threadIdx.x;
    const int m = gb >> 8;
    const int wid = tid >> 6, lane = tid & 63;
    const int row = (gb & 255) * 16 + wid;
    const float* __restrict__ Drow = (m ? D2 : D1) + (size_t)row * N;
    const float INF = __builtin_inff();

    float4 v[16];
#pragma unroll
    for (int it = 0; it < 16; ++it)
        v[it] = *(const float4*)(Drow + it * 256 + lane * 4);

    float mn = INF, sm = 0.f;
#pragma unroll
    for (int it = 0; it < 16; ++it) {
        float a = v[it].x, b = v[it].y, c = v[it].z, d = v[it].w;
        mn = fminf(mn, a > 0.f ? a : INF);   // excludes exact-zero diagonal
        mn = fminf(mn, b > 0.f ? b : INF);
        mn = fminf(mn, c > 0.f ? c : INF);
        mn = fminf(mn, d > 0.f ? d : INF);
        sm += a + b + c + d;                 // self adds 0, harmless
    }
#pragma unroll
    for (int off = 32; off > 0; off >>= 1) {
        mn = fminf(mn, __shfl_xor(mn, off, 64));
        sm += __shfl_xor(sm, off, 64);
    }
    const float mean = sm * (1.f / 4095.f);
    const float T = mn + 0.25f * (mean - mn);

    int mycnt = 0;
#pragma unroll
    for (int it = 0; it < 16; ++it) {
        mycnt += (v[it].x > 0.f && v[it].x < T);
        mycnt += (v[it].y > 0.f && v[it].y < T);
        mycnt += (v[it].z > 0.f && v[it].z < T);
        mycnt += (v[it].w > 0.f && v[it].w < T);
    }
    int incl = mycnt;
#pragma unroll
    for (int d = 1; d < 64; d <<= 1) {
        int o = __shfl_up(incl, d, 64);
        if (lane >= d) incl += o;
    }
    const int total = __shfl(incl, 63, 64);
    int pos = incl - mycnt;

    u64* lp = lists + (size_t)m * N * LCAP + row;   // column-major: + k*N
#pragma unroll
    for (int it = 0; it < 16; ++it) {
        float e4[4] = {v[it].x, v[it].y, v[it].z, v[it].w};
#pragma unroll
        for (int s = 0; s < 4; ++s) {
            float x = e4[s];
            if (x > 0.f && x < T) {
                if (pos < LCAP)
                    lp[(size_t)pos * N] = ((u64)__float_as_uint(x) << 12) | (unsigned)(it * 256 + lane * 4 + s);
                ++pos;
            }
        }
    }
    if (lane == 0) {
        rowcount[m * N + row] = total;   // > LCAP marks overflow
        rthresh[m * N + row] = T;
    }
}

// One workgroup per matrix: all Boruvka rounds + Euler-tour rooting, one dispatch.
__global__ __launch_bounds__(1024) void solve_kernel(const float* __restrict__ D1,
                                                     const float* __restrict__ D2,
                                                     const int* __restrict__ rcnt,
                                                     const float* __restrict__ rthr,
                                                     const u64* __restrict__ lists,
                                                     int2* __restrict__ edges_g,
                                                     int* __restrict__ parent_g) {
    const int m = blockIdx.x;
    const int tid = threadIdx.x;
    const int wid = tid >> 6, lane = tid & 63;
    const float* __restrict__ D = m ? D2 : D1;
    const int* __restrict__ grc = rcnt + m * N;
    const float* __restrict__ gth = rthr + m * N;
    const u64* __restrict__ gls = lists + (size_t)m * N * LCAP;
    int2* __restrict__ ged = edges_g + (size_t)m * N;
    int* __restrict__ gpar = parent_g + m * N;

    __shared__ __align__(16) char SM[57344];   // 56 KB arena, phase-aliased
    int* scomp = (int*)SM;                     // rounds: 16 KB @0
    u64* scand = (u64*)(SM + 16384);           // rounds: 32 KB @16K
    u16* sresc = (u16*)(SM + 49152);           // rounds: 8 KB @48K (aliased slink)
    __shared__ int sdone, secnt, snres, scnt, swar[16];

    for (int i = tid; i < N; i += 1024) { scomp[i] = i; scand[i] = INFKEY; }
    if (tid == 0) { sdone = 0; secnt = 0; }
    __syncthreads();

    for (int round = 0; round < ROUNDS; ++round) {
        if (sdone) break;
        if (tid == 0) snres = 0;
        __syncthreads();

        // ---- phase 1: exact row cross-min from candidate list (coalesced) ----
        for (int row = tid; row < N; row += 1024) {
            int c = scomp[row];
            int cnt = grc[row];
            int flag = 0;
            if (cnt > LCAP) {
                flag = 2;                       // overflow: bound invalid, must rescan
            } else {
                u64 best = INFKEY;
                const u64* lp = gls + row;
#pragma unroll 4
                for (int k = 0; k < cnt; ++k) {
                    u64 e = lp[(size_t)k * N];
                    int j = (int)(e & 0xFFF);
                    if (scomp[j] != c && e < best) best = e;
                }
                if (best != INFKEY)
                    atomicMin(&scand[c], ((best >> 12) << 24) | ((u64)row << 12) | (best & 0xFFF));
                else
                    flag = 1;                   // exhausted: true cross-min >= T_row
            }
            if (flag) {
                int i = atomicAdd(&snres, 1);
                sresc[i] = (u16)(row | (flag == 2 ? 0x2000 : 0x1000));
            }
        }
        __syncthreads();

        // ---- phase 2: filter exhausted rows that cannot beat comp candidate ----
        for (int i = tid; i < snres; i += 1024) {
            u16 e = sresc[i];
            if (e & 0x1000) {
                int row = e & 0xFFF;
                int c = scomp[row];
                u64 cc = scand[c];
                float w = (cc == INFKEY) ? __builtin_inff()
                                         : __uint_as_float((unsigned)(cc >> 24));
                if (!(gth[row] < w)) sresc[i] = 0xFFFF;
            }
        }
        __syncthreads();

        // ---- phase 3: full row rescan, one wave per surviving entry ----
        {
            int nres = snres;
            for (int i = wid; i < nres; i += 16) {
                u16 e = sresc[i];
                if (e == 0xFFFF) continue;
                int row = (int)(e & 0xFFF);
                int c = scomp[row];
                const float* Drow = D + (size_t)row * N;
                u64 best = INFKEY;
                for (int j0 = lane * 4; j0 < N; j0 += 256) {
                    float4 d = *(const float4*)(Drow + j0);
                    int4 cj = *(const int4*)(scomp + j0);
                    if (cj.x != c) { u64 k = ((u64)__float_as_uint(d.x) << 12) | (unsigned)(j0 + 0); if (k < best) best = k; }
                    if (cj.y != c) { u64 k = ((u64)__float_as_uint(d.y) << 12) | (unsigned)(j0 + 1); if (k < best) best = k; }
                    if (cj.z != c) { u64 k = ((u64)__float_as_uint(d.z) << 12) | (unsigned)(j0 + 2); if (k < best) best = k; }
                    if (cj.w != c) { u64 k = ((u64)__float_as_uint(d.w) << 12) | (unsigned)(j0 + 3); if (k < best) best = k; }
                }
#pragma unroll
                for (int off = 32; off > 0; off >>= 1) {
                    u64 o = __shfl_xor(best, off, 64);
                    if (o < best) best = o;
                }
                if (lane == 0 && best != INFKEY)
                    atomicMin(&scand[c], ((best >> 12) << 24) | ((u64)row << 12) | (best & 0xFFF));
            }
        }
        __syncthreads();

        // ---- phase 4: hook roots, record edges, compress (root-walk), check ----
        u16* slink = sresc;
        for (int c = tid; c < N; c += 1024) {
            int l = scomp[c];
            if (l == c) {
                u64 k = scand[c];
                if (k != INFKEY) {
                    int v = (int)(k & 0xFFF);
                    int u = (int)((k >> 12) & 0xFFF);
                    int t = scomp[v];
                    u64 tk = scand[t];
                    int mutual = 0;
                    if (tk != INFKEY) {
                        int tv = (int)(tk & 0xFFF);
                        mutual = (scomp[tv] == c);
                    }
                    if (mutual) {
                        if (c < t) { int idx = atomicAdd(&secnt, 1); ged[idx] = make_int2(u, v); }
                        else l = t;
                    } else {
                        int idx = atomicAdd(&secnt, 1); ged[idx] = make_int2(u, v); l = t;
                    }
                }
            }
            slink[c] = (u16)l;
        }
        __syncthreads();
        for (int c = tid; c < N; c += 1024) scomp[c] = slink[c];
        __syncthreads();
        // concurrent root-walk compression: links form a static forest (2-cycles
        // resolved); any concurrently-written value is itself a root -> monotone.
        for (int c = tid; c < N; c += 1024) {
            int r = scomp[c];
            int n = scomp[r];
            while (n != r) { r = n; n = scomp[r]; }
            scomp[c] = r;
        }
        __syncthreads();
        if (tid == 0) scnt = 0;
        __syncthreads();
        int local = 0;
        for (int c = tid; c < N; c += 1024) local += (scomp[c] == c) ? 1 : 0;
        atomicAdd(&scnt, local);
        __syncthreads();
        if (tid == 0 && scnt == 1) sdone = 1;
        for (int c = tid; c < N; c += 1024) scand[c] = INFKEY;
        __syncthreads();
    }

    // ================= Euler-tour rooting (depth-independent) =================
    // Arena aliasing (rounds data dead):
    //   uvp  u32[4095] @0      (16K)  packed (u<<16)|v per undirected edge
    //   off  u16[4096] @16K    (8K)   degree counts -> exclusive offsets -> end-offsets
    //   adj  u16[8192] @24K    (16K)  adjacency list of directed-edge ids
    //   succ u16[8192] @40K    (16K)  slot-temp -> Euler successor
    //   rnk  u16[8192] @16K    (16K)  aliases off+adj[0..4095] (both dead when written)
    //   minp u32[4096] @40K    (16K)  aliases succ (dead after ranking)
    u32* uvp  = (u32*)SM;
    u16* off  = (u16*)(SM + 16384);
    u16* adj  = (u16*)(SM + 24576);
    u16* succ = (u16*)(SM + 40960);
    u16* rnk  = (u16*)(SM + 16384);
    u32* minp = (u32*)(SM + 40960);

    __syncthreads();
    for (int i = tid; i < EC; i += 1024) {
        int2 e = ged[i];
        uvp[i] = ((u32)e.x << 16) | (u32)e.y;
    }
    for (int i = tid; i < 2048; i += 1024) ((u32*)off)[i] = 0;
    __syncthreads();
    // degree count (u16 halves packed in u32 for LDS atomics; no overflow, deg < 4096)
    for (int i = tid; i < EC; i += 1024) {
        u32 w = uvp[i];
        int u = (int)(w >> 16), v = (int)(w & 0xFFFF);
        atomicAdd((u32*)off + (u >> 1), 1u << ((u & 1) * 16));
        atomicAdd((u32*)off + (v >> 1), 1u << ((v & 1) * 16));
    }
    __syncthreads();
    // exclusive prefix scan of 4096 degrees (4/thread -> wave scan -> 16-wave scan)
    {
        const int i0 = tid * 4;
        int d0 = off[i0], d1 = off[i0 + 1], d2 = off[i0 + 2], d3 = off[i0 + 3];
        int t0 = d0, t01 = d0 + d1, t012 = t01 + d2, tot = t012 + d3;
        int inc = tot;
#pragma unroll
        for (int d = 1; d < 64; d <<= 1) {
            int o = __shfl_up(inc, d, 64);
            if (lane >= d) inc += o;
        }
        if (lane == 63) swar[wid] = inc;
        __syncthreads();
        if (wid == 0) {
            int v = (lane < 16) ? swar[lane] : 0;
            int vin = v;
#pragma unroll
            for (int d = 1; d < 16; d <<= 1) {
                int o = __shfl_up(v, d, 64);
                if (lane >= d) v += o;
            }
            if (lane < 16) swar[lane] = v - vin;   // exclusive wave base
        }
        __syncthreads();
        int base = swar[wid] + (inc - tot);
        off[i0] = (u16)base;
        off[i0 + 1] = (u16)(base + t0);
        off[i0 + 2] = (u16)(base + t01);
        off[i0 + 3] = (u16)(base + t012);
    }
    __syncthreads();
    // fill adjacency; off[v] becomes end-offset (= excl offset of v+1); start(v) = off[v-1]
    for (int e = tid; e < M2; e += 1024) {
        int i = e >> 1;
        u32 w = uvp[i];
        int src = (e & 1) ? (int)(w & 0xFFFF) : (int)(w >> 16);
        u32 old = atomicAdd((u32*)off + (src >> 1), 1u << ((src & 1) * 16));
        u32 slot = (old >> ((src & 1) * 16)) & 0xFFFFu;
        adj[slot] = (u16)e;
        succ[e] = (u16)slot;                 // temp: my slot
    }
    __syncthreads();
    const int e0 = adj[0];                   // first edge out of vertex 0 = tour start
    // successor: rotate around dst(e) from twin's slot (reg-staged, then write)
    {
        u16 nsv[8];
        int k = 0;
        for (int e = tid; e < M2; e += 1024) {
            int i = e >> 1;
            u32 w = uvp[i];
            int v = (e & 1) ? (int)(w >> 16) : (int)(w & 0xFFFF);   // dst(e)
            int st = succ[e ^ 1];
            int start = (v == 0) ? 0 : off[v - 1];
            int end = off[v];
            int ns = (st + 1 < end) ? st + 1 : start;
            nsv[k++] = adj[ns];
        }
        __syncthreads();
        k = 0;
        for (int e = tid; e < M2; e += 1024) succ[e] = nsv[k++];
    }
    __syncthreads();
    // init ranks; terminate the unique predecessor of e0 (rnk clobbers off/adj - both dead)
    for (int e = tid; e < M2; e += 1024) {
        u16 s = succ[e];
        if (s == (u16)e0) { succ[e] = (u16)e; rnk[e] = 0; }
        else rnk[e] = 1;
    }
    __syncthreads();
    // list ranking: 13 pointer-jump iterations (2^13 >= 8190)
    for (int it = 0; it < 13; ++it) {
        u16 nr[8], s2[8];
        int k = 0;
        for (int e = tid; e < M2; e += 1024) {
            u16 s1 = succ[e];
            u16 r1 = rnk[e];
            nr[k] = (u16)(r1 + rnk[s1]);   // rnk[term]=0, succ[term]=term -> stable
            s2[k] = succ[s1];
            ++k;
        }
        __syncthreads();
        k = 0;
        for (int e = tid; e < M2; e += 1024) { rnk[e] = nr[k]; succ[e] = s2[k]; ++k; }
        __syncthreads();
    }
    // first entry into v = min tour position among incoming edges (minp clobbers succ)
    for (int i = tid; i < N; i += 1024) minp[i] = 0xFFFFFFFFu;
    __syncthreads();
    for (int e = tid; e < M2; e += 1024) {
        int i = e >> 1;
        u32 w = uvp[i];
        int dst = (e & 1) ? (int)(w >> 16) : (int)(w & 0xFFFF);
        int srcv = (e & 1) ? (int)(w & 0xFFFF) : (int)(w >> 16);
        u32 p = (u32)(M2 - 1) - (u32)rnk[e];
        atomicMin(&minp[dst], (p << 16) | (u32)srcv);
    }
    __syncthreads();
    for (int v = tid; v < N; v += 1024) gpar[v] = (v == 0) ? 0 : (int)(minp[v] & 0xFFFFu);
}

__global__ __launch_bounds__(1024) void finalize_kernel(const float* __restrict__ D1,
                                                        const float* __restrict__ D2,
                                                        const int* __restrict__ parent,
                                                        float* __restrict__ out) {
    __shared__ float rs12[16], rs21[16];
    __shared__ int rm[16];
    const int tid = threadIdx.x;
    const int* p1 = parent;
    const int* p2 = parent + N;

    float s12 = 0.f, s21 = 0.f;
    int mcnt = 0;
    for (int c = 1 + tid; c < N; c += 1024) {
        int a = p1[c];
        int b = p2[c];
        float e1 = D1[(size_t)a * N + c] - D2[(size_t)a * N + c];
        float e2 = D2[(size_t)b * N + c] - D1[(size_t)b * N + c];
        s12 += e1 * e1;
        s21 += e2 * e2;
        mcnt += (a == b) ? 1 : 0;
    }
#pragma unroll
    for (int off = 32; off > 0; off >>= 1) {
        s12 += __shfl_xor(s12, off, 64);
        s21 += __shfl_xor(s21, off, 64);
        mcnt += __shfl_xor(mcnt, off, 64);
    }
    const int wid = tid >> 6, lane = tid & 63;
    if (lane == 0) { rs12[wid] = s12; rs21[wid] = s21; rm[wid] = mcnt; }
    __syncthreads();
    if (tid == 0) {
        float a = 0.f, b = 0.f;
        int mm = 0;
#pragma unroll
        for (int w = 0; w < 16; ++w) { a += rs12[w]; b += rs21[w]; mm += rm[w]; }
        float d12 = sqrtf(a);
        float d21 = sqrtf(b);
        out[0] = d12 + d21;
        out[1] = d12;
        out[2] = d21;
        out[3] = (float)mm;
    }
}

extern "C" void kernel_launch(void* const* d_in, const int* in_sizes, int n_in,
                              void* d_out, int out_size, void* d_ws, size_t ws_size,
                              hipStream_t stream) {
    const float* D1 = (const float*)d_in[0];
    const float* D2 = (const float*)d_in[1];

    int* parent = WS_PARENT(d_ws);
    int* rcnt = WS_RCNT(d_ws);
    float* rthr = WS_RTHR(d_ws);
    int2* edges = WS_EDGES(d_ws);
    u64* lists = WS_LISTS(d_ws);

    build_kernel<<<512, 1024, 0, stream>>>(D1, D2, rcnt, rthr, lists);
    solve_kernel<<<2, 1024, 0, stream>>>(D1, D2, rcnt, rthr, lists, edges, parent);
    finalize_kernel<<<1, 1024, 0, stream>>>(D1, D2, parent, (float*)d_out);
}

// Round 6
// 385.943 us; speedup vs baseline: 1.4488x; 1.1724x over previous
//
#include <hip/hip_runtime.h>
#include <math.h>

#define N 4096
#define ROUNDS 12           // components at least halve per round: 4096 -> 1 guaranteed
#define INFKEY 0xFFFFFFFFFFFFFFFFULL
#define LCAP 48             // candidate-list capacity per row
#define EC (N - 1)          // MST edge count
#define M2 (2 * EC)         // directed edges (8190)

typedef unsigned long long u64;
typedef unsigned int u32;
typedef unsigned short u16;

// ---- workspace layout (bytes) ----
#define WS_PARENT(ws) ((int*)((char*)(ws) + 0))          // int[2N]    32 KB
#define WS_RCNT(ws)   ((int*)((char*)(ws) + 32768))      // int[2N]    32 KB
#define WS_RTHR(ws)   ((float*)((char*)(ws) + 65536))    // float[2N]  32 KB
#define WS_EDGES(ws)  ((int2*)((char*)(ws) + 98304))     // int2[2N]   64 KB
#define WS_LISTS(ws)  ((u64*)((char*)(ws) + 163840))     // u64[2N*LCAP] 3 MB, column-major per matrix

// cand key: (float_bits(w) << 24) | (u << 12) | v    (56 bits)
// list entry: (float_bits(w) << 12) | j              (44 bits)
// distances >= 0 -> float bit pattern order-preserving; weights unique (fp32 Gaussian).

// One wave per row, one full-matrix streaming pass. Threshold T starts at
// min + 0.25*(mean-min) and the gap is HALVED (recount from registers) until
// count <= LCAP: every row then has a complete ball list and a VALID bound,
// so the solver's phase-2 filter applies to every exhausted row (the old
// overflow class rescanned 16KB every round -- that was ~40 us/round).
__global__ __launch_bounds__(1024) void build_kernel(const float* __restrict__ D1,
                                                     const float* __restrict__ D2,
                                                     int* __restrict__ rowcount,
                                                     float* __restrict__ rthresh,
                                                     u64* __restrict__ lists) {
    const int gb = blockIdx.x;   // 512 blocks: 256 per matrix
    const int tid = threadIdx.x;
    const int m = gb >> 8;
    const int wid = tid >> 6, lane = tid & 63;
    const int row = (gb & 255) * 16 + wid;
    const float* __restrict__ Drow = (m ? D2 : D1) + (size_t)row * N;
    const float INF = __builtin_inff();

    float4 v[16];
#pragma unroll
    for (int it = 0; it < 16; ++it)
        v[it] = *(const float4*)(Drow + it * 256 + lane * 4);

    float mn = INF, sm = 0.f;
#pragma unroll
    for (int it = 0; it < 16; ++it) {
        float a = v[it].x, b = v[it].y, c = v[it].z, d = v[it].w;
        mn = fminf(mn, a > 0.f ? a : INF);   // excludes exact-zero diagonal
        mn = fminf(mn, b > 0.f ? b : INF);
        mn = fminf(mn, c > 0.f ? c : INF);
        mn = fminf(mn, d > 0.f ? d : INF);
        sm += a + b + c + d;                 // self adds 0, harmless
    }
#pragma unroll
    for (int off = 32; off > 0; off >>= 1) {
        mn = fminf(mn, __shfl_xor(mn, off, 64));
        sm += __shfl_xor(sm, off, 64);
    }
    const float mean = sm * (1.f / 4095.f);
    float T = mn + 0.25f * (mean - mn);

    // adaptive shrink: count < T, halve gap until count <= LCAP (regs only).
    // T > mn always => count >= 1 (the row min stays in the list).
    int mycnt, total;
    for (int iter = 0; iter < 10; ++iter) {
        mycnt = 0;
#pragma unroll
        for (int it = 0; it < 16; ++it) {
            mycnt += (v[it].x > 0.f && v[it].x < T);
            mycnt += (v[it].y > 0.f && v[it].y < T);
            mycnt += (v[it].z > 0.f && v[it].z < T);
            mycnt += (v[it].w > 0.f && v[it].w < T);
        }
        total = mycnt;
#pragma unroll
        for (int off = 32; off > 0; off >>= 1) total += __shfl_xor(total, off, 64);
        if (total <= LCAP) break;
        T = mn + 0.5f * (T - mn);
    }

    // 64-lane exclusive position scan
    int incl = mycnt;
#pragma unroll
    for (int d = 1; d < 64; d <<= 1) {
        int o = __shfl_up(incl, d, 64);
        if (lane >= d) incl += o;
    }
    int pos = incl - mycnt;

    u64* lp = lists + (size_t)m * N * LCAP + row;   // column-major: + k*N
#pragma unroll
    for (int it = 0; it < 16; ++it) {
        float e4[4] = {v[it].x, v[it].y, v[it].z, v[it].w};
#pragma unroll
        for (int s = 0; s < 4; ++s) {
            float x = e4[s];
            if (x > 0.f && x < T) {
                if (pos < LCAP)
                    lp[(size_t)pos * N] = ((u64)__float_as_uint(x) << 12) | (unsigned)(it * 256 + lane * 4 + s);
                ++pos;
            }
        }
    }
    if (lane == 0) {
        rowcount[m * N + row] = total;   // <= LCAP after adaptive shrink
        rthresh[m * N + row] = T;
    }
}

// One workgroup per matrix: all Boruvka rounds + Euler-tour rooting, one dispatch.
__global__ __launch_bounds__(1024) void solve_kernel(const float* __restrict__ D1,
                                                     const float* __restrict__ D2,
                                                     const int* __restrict__ rcnt,
                                                     const float* __restrict__ rthr,
                                                     const u64* __restrict__ lists,
                                                     int2* __restrict__ edges_g,
                                                     int* __restrict__ parent_g) {
    const int m = blockIdx.x;
    const int tid = threadIdx.x;
    const int wid = tid >> 6, lane = tid & 63;
    const float* __restrict__ D = m ? D2 : D1;
    const int* __restrict__ grc = rcnt + m * N;
    const float* __restrict__ gth = rthr + m * N;
    const u64* __restrict__ gls = lists + (size_t)m * N * LCAP;
    int2* __restrict__ ged = edges_g + (size_t)m * N;
    int* __restrict__ gpar = parent_g + m * N;

    __shared__ __align__(16) char SM[57344];   // 56 KB arena, phase-aliased
    int* scomp = (int*)SM;                     // rounds: 16 KB @0
    u64* scand = (u64*)(SM + 16384);           // rounds: 32 KB @16K
    u16* sresc = (u16*)(SM + 49152);           // rounds: 8 KB @48K (aliased slink)
    __shared__ int sdone, secnt, snres, scnt, swar[16];

    for (int i = tid; i < N; i += 1024) { scomp[i] = i; scand[i] = INFKEY; }
    if (tid == 0) { sdone = 0; secnt = 0; }
    __syncthreads();

    for (int round = 0; round < ROUNDS; ++round) {
        if (sdone) break;
        if (tid == 0) snres = 0;
        __syncthreads();

        // ---- phase 1: exact row cross-min from candidate list (coalesced) ----
        for (int row = tid; row < N; row += 1024) {
            int c = scomp[row];
            int cnt = grc[row];
            int flag = 0;
            if (cnt > LCAP) {
                flag = 2;                       // defensive; empty class after adaptive build
            } else {
                u64 best = INFKEY;
                const u64* lp = gls + row;
#pragma unroll 4
                for (int k = 0; k < cnt; ++k) {
                    u64 e = lp[(size_t)k * N];
                    int j = (int)(e & 0xFFF);
                    if (scomp[j] != c && e < best) best = e;
                }
                if (best != INFKEY) {
                    u64 key = ((best >> 12) << 24) | ((u64)row << 12) | (best & 0xFFF);
                    if (key < scand[c]) atomicMin(&scand[c], key);   // guarded: kills RMW serialization
                } else
                    flag = 1;                   // exhausted: true cross-min >= T_row
            }
            if (flag) {
                int i = atomicAdd(&snres, 1);
                sresc[i] = (u16)(row | (flag == 2 ? 0x2000 : 0x1000));
            }
        }
        __syncthreads();

        // ---- phase 2: filter exhausted rows that cannot beat comp candidate ----
        // scand quiescent (barrier). Skip is safe: cand only decreases and
        // row cross-min >= T_row >= current w >= final w.
        for (int i = tid; i < snres; i += 1024) {
            u16 e = sresc[i];
            if (e & 0x1000) {
                int row = e & 0xFFF;
                int c = scomp[row];
                u64 cc = scand[c];
                float w = (cc == INFKEY) ? __builtin_inff()
                                         : __uint_as_float((unsigned)(cc >> 24));
                if (!(gth[row] < w)) sresc[i] = 0xFFFF;
            }
        }
        __syncthreads();

        // ---- phase 3: full row rescan, one wave per surviving entry ----
        {
            int nres = snres;
            for (int i = wid; i < nres; i += 16) {
                u16 e = sresc[i];
                if (e == 0xFFFF) continue;
                int row = (int)(e & 0xFFF);
                int c = scomp[row];
                const float* Drow = D + (size_t)row * N;
                u64 best = INFKEY;
                for (int j0 = lane * 4; j0 < N; j0 += 256) {
                    float4 d = *(const float4*)(Drow + j0);
                    int4 cj = *(const int4*)(scomp + j0);
                    if (cj.x != c) { u64 k = ((u64)__float_as_uint(d.x) << 12) | (unsigned)(j0 + 0); if (k < best) best = k; }
                    if (cj.y != c) { u64 k = ((u64)__float_as_uint(d.y) << 12) | (unsigned)(j0 + 1); if (k < best) best = k; }
                    if (cj.z != c) { u64 k = ((u64)__float_as_uint(d.z) << 12) | (unsigned)(j0 + 2); if (k < best) best = k; }
                    if (cj.w != c) { u64 k = ((u64)__float_as_uint(d.w) << 12) | (unsigned)(j0 + 3); if (k < best) best = k; }
                }
#pragma unroll
                for (int off = 32; off > 0; off >>= 1) {
                    u64 o = __shfl_xor(best, off, 64);
                    if (o < best) best = o;
                }
                if (lane == 0 && best != INFKEY) {
                    u64 key = ((best >> 12) << 24) | ((u64)row << 12) | (best & 0xFFF);
                    if (key < scand[c]) atomicMin(&scand[c], key);
                }
            }
        }
        __syncthreads();

        // ---- phase 4: hook roots, record edges, compress (root-walk), check ----
        u16* slink = sresc;
        for (int c = tid; c < N; c += 1024) {
            int l = scomp[c];
            if (l == c) {
                u64 k = scand[c];
                if (k != INFKEY) {
                    int v = (int)(k & 0xFFF);
                    int u = (int)((k >> 12) & 0xFFF);
                    int t = scomp[v];
                    u64 tk = scand[t];
                    int mutual = 0;
                    if (tk != INFKEY) {
                        int tv = (int)(tk & 0xFFF);
                        mutual = (scomp[tv] == c);
                    }
                    if (mutual) {
                        if (c < t) { int idx = atomicAdd(&secnt, 1); ged[idx] = make_int2(u, v); }
                        else l = t;
                    } else {
                        int idx = atomicAdd(&secnt, 1); ged[idx] = make_int2(u, v); l = t;
                    }
                }
            }
            slink[c] = (u16)l;
        }
        __syncthreads();
        for (int c = tid; c < N; c += 1024) scomp[c] = slink[c];
        __syncthreads();
        // concurrent root-walk compression: links form a static forest (2-cycles
        // resolved); any concurrently-written value is itself a root -> monotone.
        for (int c = tid; c < N; c += 1024) {
            int r = scomp[c];
            int n = scomp[r];
            while (n != r) { r = n; n = scomp[r]; }
            scomp[c] = r;
        }
        __syncthreads();
        if (tid == 0) scnt = 0;
        __syncthreads();
        int local = 0;
        for (int c = tid; c < N; c += 1024) local += (scomp[c] == c) ? 1 : 0;
        atomicAdd(&scnt, local);
        __syncthreads();
        if (tid == 0 && scnt == 1) sdone = 1;
        for (int c = tid; c < N; c += 1024) scand[c] = INFKEY;
        __syncthreads();
    }

    // ================= Euler-tour rooting (depth-independent) =================
    u32* uvp  = (u32*)SM;                      // 16K @0
    u16* off  = (u16*)(SM + 16384);            // 8K
    u16* adj  = (u16*)(SM + 24576);            // 16K
    u16* succ = (u16*)(SM + 40960);            // 16K
    u16* rnk  = (u16*)(SM + 16384);            // aliases off+adj (dead)
    u32* minp = (u32*)(SM + 40960);            // aliases succ (dead)

    __syncthreads();
    for (int i = tid; i < EC; i += 1024) {
        int2 e = ged[i];
        uvp[i] = ((u32)e.x << 16) | (u32)e.y;
    }
    for (int i = tid; i < 2048; i += 1024) ((u32*)off)[i] = 0;
    __syncthreads();
    for (int i = tid; i < EC; i += 1024) {
        u32 w = uvp[i];
        int u = (int)(w >> 16), v = (int)(w & 0xFFFF);
        atomicAdd((u32*)off + (u >> 1), 1u << ((u & 1) * 16));
        atomicAdd((u32*)off + (v >> 1), 1u << ((v & 1) * 16));
    }
    __syncthreads();
    {
        const int i0 = tid * 4;
        int d0 = off[i0], d1 = off[i0 + 1], d2 = off[i0 + 2], d3 = off[i0 + 3];
        int t0 = d0, t01 = d0 + d1, t012 = t01 + d2, tot = t012 + d3;
        int inc = tot;
#pragma unroll
        for (int d = 1; d < 64; d <<= 1) {
            int o = __shfl_up(inc, d, 64);
            if (lane >= d) inc += o;
        }
        if (lane == 63) swar[wid] = inc;
        __syncthreads();
        if (wid == 0) {
            int v = (lane < 16) ? swar[lane] : 0;
            int vin = v;
#pragma unroll
            for (int d = 1; d < 16; d <<= 1) {
                int o = __shfl_up(v, d, 64);
                if (lane >= d) v += o;
            }
            if (lane < 16) swar[lane] = v - vin;
        }
        __syncthreads();
        int base = swar[wid] + (inc - tot);
        off[i0] = (u16)base;
        off[i0 + 1] = (u16)(base + t0);
        off[i0 + 2] = (u16)(base + t01);
        off[i0 + 3] = (u16)(base + t012);
    }
    __syncthreads();
    for (int e = tid; e < M2; e += 1024) {
        int i = e >> 1;
        u32 w = uvp[i];
        int src = (e & 1) ? (int)(w & 0xFFFF) : (int)(w >> 16);
        u32 old = atomicAdd((u32*)off + (src >> 1), 1u << ((src & 1) * 16));
        u32 slot = (old >> ((src & 1) * 16)) & 0xFFFFu;
        adj[slot] = (u16)e;
        succ[e] = (u16)slot;                 // temp: my slot
    }
    __syncthreads();
    const int e0 = adj[0];                   // first edge out of vertex 0 = tour start
    {
        u16 nsv[8];
        int k = 0;
        for (int e = tid; e < M2; e += 1024) {
            int i = e >> 1;
            u32 w = uvp[i];
            int v = (e & 1) ? (int)(w >> 16) : (int)(w & 0xFFFF);   // dst(e)
            int st = succ[e ^ 1];
            int start = (v == 0) ? 0 : off[v - 1];
            int end = off[v];
            int ns = (st + 1 < end) ? st + 1 : start;
            nsv[k++] = adj[ns];
        }
        __syncthreads();
        k = 0;
        for (int e = tid; e < M2; e += 1024) succ[e] = nsv[k++];
    }
    __syncthreads();
    for (int e = tid; e < M2; e += 1024) {
        u16 s = succ[e];
        if (s == (u16)e0) { succ[e] = (u16)e; rnk[e] = 0; }
        else rnk[e] = 1;
    }
    __syncthreads();
    for (int it = 0; it < 13; ++it) {
        u16 nr[8], s2[8];
        int k = 0;
        for (int e = tid; e < M2; e += 1024) {
            u16 s1 = succ[e];
            u16 r1 = rnk[e];
            nr[k] = (u16)(r1 + rnk[s1]);
            s2[k] = succ[s1];
            ++k;
        }
        __syncthreads();
        k = 0;
        for (int e = tid; e < M2; e += 1024) { rnk[e] = nr[k]; succ[e] = s2[k]; ++k; }
        __syncthreads();
    }
    for (int i = tid; i < N; i += 1024) minp[i] = 0xFFFFFFFFu;
    __syncthreads();
    for (int e = tid; e < M2; e += 1024) {
        int i = e >> 1;
        u32 w = uvp[i];
        int dst = (e & 1) ? (int)(w >> 16) : (int)(w & 0xFFFF);
        int srcv = (e & 1) ? (int)(w & 0xFFFF) : (int)(w >> 16);
        u32 p = (u32)(M2 - 1) - (u32)rnk[e];
        atomicMin(&minp[dst], (p << 16) | (u32)srcv);
    }
    __syncthreads();
    for (int v = tid; v < N; v += 1024) gpar[v] = (v == 0) ? 0 : (int)(minp[v] & 0xFFFFu);
}

__global__ __launch_bounds__(1024) void finalize_kernel(const float* __restrict__ D1,
                                                        const float* __restrict__ D2,
                                                        const int* __restrict__ parent,
                                                        float* __restrict__ out) {
    __shared__ float rs12[16], rs21[16];
    __shared__ int rm[16];
    const int tid = threadIdx.x;
    const int* p1 = parent;
    const int* p2 = parent + N;

    float s12 = 0.f, s21 = 0.f;
    int mcnt = 0;
    for (int c = 1 + tid; c < N; c += 1024) {
        int a = p1[c];
        int b = p2[c];
        float e1 = D1[(size_t)a * N + c] - D2[(size_t)a * N + c];
        float e2 = D2[(size_t)b * N + c] - D1[(size_t)b * N + c];
        s12 += e1 * e1;
        s21 += e2 * e2;
        mcnt += (a == b) ? 1 : 0;
    }
#pragma unroll
    for (int off = 32; off > 0; off >>= 1) {
        s12 += __shfl_xor(s12, off, 64);
        s21 += __shfl_xor(s21, off, 64);
        mcnt += __shfl_xor(mcnt, off, 64);
    }
    const int wid = tid >> 6, lane = tid & 63;
    if (lane == 0) { rs12[wid] = s12; rs21[wid] = s21; rm[wid] = mcnt; }
    __syncthreads();
    if (tid == 0) {
        float a = 0.f, b = 0.f;
        int mm = 0;
#pragma unroll
        for (int w = 0; w < 16; ++w) { a += rs12[w]; b += rs21[w]; mm += rm[w]; }
        float d12 = sqrtf(a);
        float d21 = sqrtf(b);
        out[0] = d12 + d21;
        out[1] = d12;
        out[2] = d21;
        out[3] = (float)mm;
    }
}

extern "C" void kernel_launch(void* const* d_in, const int* in_sizes, int n_in,
                              void* d_out, int out_size, void* d_ws, size_t ws_size,
                              hipStream_t stream) {
    const float* D1 = (const float*)d_in[0];
    const float* D2 = (const float*)d_in[1];

    int* parent = WS_PARENT(d_ws);
    int* rcnt = WS_RCNT(d_ws);
    float* rthr = WS_RTHR(d_ws);
    int2* edges = WS_EDGES(d_ws);
    u64* lists = WS_LISTS(d_ws);

    build_kernel<<<512, 1024, 0, stream>>>(D1, D2, rcnt, rthr, lists);
    solve_kernel<<<2, 1024, 0, stream>>>(D1, D2, rcnt, rthr, lists, edges, parent);
    finalize_kernel<<<1, 1024, 0, stream>>>(D1, D2, parent, (float*)d_out);
}

// Round 7
// 335.725 us; speedup vs baseline: 1.6655x; 1.1496x over previous
//
#include <hip/hip_runtime.h>
#include <math.h>

#define N 4096
#define ROUNDS 12           // components at least halve per round: 4096 -> 1 guaranteed
#define INFKEY 0xFFFFFFFFFFFFFFFFULL
#define LCAP 48             // candidate-list capacity per row (<= 64: one lane per entry)
#define EC (N - 1)          // MST edge count
#define M2 (2 * EC)         // directed edges (8190)
#define MBLK 32             // blocks per matrix
#define RPB (N / MBLK)      // 128 rows per block
#define RPW (RPB / 16)      // 8 rows per wave

typedef unsigned long long u64;
typedef unsigned int u32;
typedef unsigned short u16;

// ---- workspace layout (bytes) ----
#define WS_PARENT(ws) ((int*)((char*)(ws) + 0))          // int[2N]    32 KB
#define WS_RCNT(ws)   ((int*)((char*)(ws) + 32768))      // int[2N]    32 KB
#define WS_RTHR(ws)   ((float*)((char*)(ws) + 65536))    // float[2N]  32 KB
#define WS_EDGES(ws)  ((int2*)((char*)(ws) + 98304))     // int2[2N]   64 KB
#define WS_COMP(ws)   ((int*)((char*)(ws) + 163840))     // int[2N]    32 KB
#define WS_CAND(ws)   ((u64*)((char*)(ws) + 196608))     // u64[2N]    64 KB
#define WS_META(ws)   ((int*)((char*)(ws) + 262144))     // int[64]: per-matrix {done,cnt,gen} at m*16
#define WS_LISTS(ws)  ((u64*)((char*)(ws) + 262400))     // u64[2N*LCAP] 3 MB, ROW-major

// cand key: (float_bits(w) << 24) | (u << 12) | v    (56 bits)
// list entry: (float_bits(w) << 12) | j              (44 bits)

// Per-matrix spin barrier over MBLK co-resident blocks (grid 64 <= 256 CUs ->
// all blocks resident; 1 block/CU at 57 KB LDS). __threadfence = agent-scope
// release/acquire (L2 writeback/invalidate on gfx95x) covers the plain-store
// data (comp, done); cand uses device-scope atomicMin RMWs.
__device__ __forceinline__ void mat_barrier(int* cnt, int* gen, int target) {
    __syncthreads();
    if (threadIdx.x == 0) {
        __threadfence();
        int old = atomicAdd(cnt, 1);
        if (old == MBLK - 1) {
            __hip_atomic_store(cnt, 0, __ATOMIC_RELAXED, __HIP_MEMORY_SCOPE_AGENT);
            __hip_atomic_store(gen, target, __ATOMIC_RELEASE, __HIP_MEMORY_SCOPE_AGENT);
        } else {
            while (__hip_atomic_load(gen, __ATOMIC_ACQUIRE, __HIP_MEMORY_SCOPE_AGENT) < target)
                __builtin_amdgcn_s_sleep(8);
        }
        __threadfence();
    }
    __syncthreads();
}

// One wave per row, one full-matrix streaming pass. Threshold T = row min +
// 0.25*(mean-min), gap halved (register recount) until count <= LCAP, so every
// row has a complete ball list AND a valid bound. Lists stored ROW-major
// (row*LCAP + k) for the solver's lane-per-entry reads. Also folds global init.
__global__ __launch_bounds__(1024) void build_kernel(const float* __restrict__ D1,
                                                     const float* __restrict__ D2,
                                                     int* __restrict__ rowcount,
                                                     float* __restrict__ rthresh,
                                                     u64* __restrict__ lists,
                                                     int* __restrict__ comp,
                                                     u64* __restrict__ cand,
                                                     int* __restrict__ meta) {
    const int gb = blockIdx.x;   // 512 blocks: 256 per matrix
    const int tid = threadIdx.x;

    // folded init (consumed only by the solve dispatch; kernel boundary orders it)
    if (gb < 2) {
        int i4 = gb * 1024 + tid;           // comp[0..8191] identity per matrix
        int b4 = i4 * 4;
        ((int4*)comp)[i4] = make_int4(b4 & (N - 1), (b4 + 1) & (N - 1),
                                      (b4 + 2) & (N - 1), (b4 + 3) & (N - 1));
    } else if (gb < 4) {
        int i = ((gb - 2) * 1024 + tid) * 4;
        cand[i] = INFKEY; cand[i + 1] = INFKEY; cand[i + 2] = INFKEY; cand[i + 3] = INFKEY;
    } else if (gb == 4 && tid < 64) {
        meta[tid] = 0;
    }

    const int m = gb >> 8;
    const int wid = tid >> 6, lane = tid & 63;
    const int row = (gb & 255) * 16 + wid;
    const float* __restrict__ Drow = (m ? D2 : D1) + (size_t)row * N;
    const float INF = __builtin_inff();

    float4 v[16];
#pragma unroll
    for (int it = 0; it < 16; ++it)
        v[it] = *(const float4*)(Drow + it * 256 + lane * 4);

    float mn = INF, sm = 0.f;
#pragma unroll
    for (int it = 0; it < 16; ++it) {
        float a = v[it].x, b = v[it].y, c = v[it].z, d = v[it].w;
        mn = fminf(mn, a > 0.f ? a : INF);   // excludes exact-zero diagonal
        mn = fminf(mn, b > 0.f ? b : INF);
        mn = fminf(mn, c > 0.f ? c : INF);
        mn = fminf(mn, d > 0.f ? d : INF);
        sm += a + b + c + d;                 // self adds 0, harmless
    }
#pragma unroll
    for (int off = 32; off > 0; off >>= 1) {
        mn = fminf(mn, __shfl_xor(mn, off, 64));
        sm += __shfl_xor(sm, off, 64);
    }
    const float mean = sm * (1.f / 4095.f);
    float T = mn + 0.25f * (mean - mn);

    int mycnt, total;
    for (int iter = 0; iter < 10; ++iter) {
        mycnt = 0;
#pragma unroll
        for (int it = 0; it < 16; ++it) {
            mycnt += (v[it].x > 0.f && v[it].x < T);
            mycnt += (v[it].y > 0.f && v[it].y < T);
            mycnt += (v[it].z > 0.f && v[it].z < T);
            mycnt += (v[it].w > 0.f && v[it].w < T);
        }
        total = mycnt;
#pragma unroll
        for (int off = 32; off > 0; off >>= 1) total += __shfl_xor(total, off, 64);
        if (total <= LCAP) break;
        T = mn + 0.5f * (T - mn);
    }

    int incl = mycnt;
#pragma unroll
    for (int d = 1; d < 64; d <<= 1) {
        int o = __shfl_up(incl, d, 64);
        if (lane >= d) incl += o;
    }
    int pos = incl - mycnt;

    u64* lp = lists + ((size_t)m * N + row) * LCAP;   // ROW-major
#pragma unroll
    for (int it = 0; it < 16; ++it) {
        float e4[4] = {v[it].x, v[it].y, v[it].z, v[it].w};
#pragma unroll
        for (int s = 0; s < 4; ++s) {
            float x = e4[s];
            if (x > 0.f && x < T) {
                if (pos < LCAP)
                    lp[pos] = ((u64)__float_as_uint(x) << 12) | (unsigned)(it * 256 + lane * 4 + s);
                ++pos;
            }
        }
    }
    if (lane == 0) {
        rowcount[m * N + row] = total;   // <= LCAP after adaptive shrink (defensive flag otherwise)
        rthresh[m * N + row] = T;
    }
}

// 32 blocks per matrix (64 total). Rounds distributed across blocks with
// per-matrix spin barriers; hook/compress on the leader block; Euler-tour
// rooting on the leader at the end.
__global__ __launch_bounds__(1024) void solve_kernel(const float* __restrict__ D1,
                                                     const float* __restrict__ D2,
                                                     const int* __restrict__ rcnt,
                                                     const float* __restrict__ rthr,
                                                     const u64* __restrict__ lists,
                                                     int* __restrict__ comp_g,
                                                     u64* __restrict__ cand_g,
                                                     int2* __restrict__ edges_g,
                                                     int* __restrict__ parent_g,
                                                     int* __restrict__ meta) {
    const int b = blockIdx.x;
    const int m = b / MBLK;
    const int bm = b - m * MBLK;
    const int tid = threadIdx.x;
    const int wid = tid >> 6, lane = tid & 63;
    const float* __restrict__ D = m ? D2 : D1;
    const int* __restrict__ grc = rcnt + m * N;
    const float* __restrict__ gth = rthr + m * N;
    const u64* __restrict__ gls = lists + (size_t)m * N * LCAP;
    int* __restrict__ gcomp = comp_g + m * N;
    u64* __restrict__ gcand = cand_g + m * N;
    int2* __restrict__ ged = edges_g + (size_t)m * N;
    int* __restrict__ gpar = parent_g + m * N;
    int* gdone = meta + m * 16;
    int* bcnt = meta + m * 16 + 1;
    int* bgen = meta + m * 16 + 2;
    const float INF = __builtin_inff();

    __shared__ __align__(16) char SM[57344];   // 56 KB arena, phase-aliased
    int* scomp = (int*)SM;                     // 16 KB @0
    u64* scand = (u64*)(SM + 16384);           // 32 KB @16K (local mirror / staged cand)
    u16* sresc = (u16*)(SM + 49152);           // 8 KB  @48K (rescan list / slink)
    __shared__ int snres, secnt, scnt, swar[16];

    if (tid == 0) secnt = 0;
    int phase = 0;

    for (int round = 0; round < ROUNDS; ++round) {
        // stage comp (post-barrier / post-kernel-boundary: coherent), reset mirrors
        for (int i = tid; i < N / 4; i += 1024) ((int4*)scomp)[i] = ((const int4*)gcomp)[i];
        for (int i = tid; i < N; i += 1024) scand[i] = INFKEY;
        if (tid == 0) snres = 0;
        __syncthreads();

        // ---- phase A: list scan, wave-per-row, lane-per-entry; block-local min ----
        for (int r = 0; r < RPW; ++r) {
            const int row = bm * RPB + wid * RPW + r;
            const int c = scomp[row];
            const int cnt = grc[row];
            const bool forced = (cnt > LCAP);   // defensive; empty class after adaptive build
            u64 best = INFKEY;
            if (!forced && lane < cnt) {
                u64 e = gls[(size_t)row * LCAP + lane];
                int j = (int)(e & 0xFFF);
                if (scomp[j] != c) best = e;
            }
#pragma unroll
            for (int off = 32; off > 0; off >>= 1) {
                u64 o = __shfl_xor(best, off, 64);
                if (o < best) best = o;
            }
            if (lane == 0) {
                if (best != INFKEY) {
                    u64 key = ((best >> 12) << 24) | ((u64)row << 12) | (best & 0xFFF);
                    if (key < scand[c]) atomicMin(&scand[c], key);   // LDS, guarded
                } else {
                    int i = atomicAdd(&snres, 1);
                    sresc[i] = (u16)(row | (forced ? 0x4000 : 0x1000));
                }
            }
        }
        __syncthreads();
        // flush block-local mins to global (<=128 atomics, <=32-way contention)
        for (int c = tid; c < N; c += 1024) {
            u64 v = scand[c];
            if (v != INFKEY) atomicMin(&gcand[c], v);
        }
        mat_barrier(bcnt, bgen, ++phase);   // A -> B

        // ---- phase B: bound filter, then rare full-row rescans ----
        for (int i = tid; i < snres; i += 1024) {
            u16 e = sresc[i];
            if (e & 0x1000) {
                int row = e & 0xFFF;
                int c = scomp[row];
                u64 cc = gcand[c];               // quiescent post-barrier
                float w = (cc == INFKEY) ? INF : __uint_as_float((u32)(cc >> 24));
                if (!(gth[row] < w)) sresc[i] = 0xFFFF;   // safe: cand only decreases
            }
        }
        __syncthreads();
        {
            const int nres = snres;
            for (int i = wid; i < nres; i += 16) {
                u16 e = sresc[i];                // wave-uniform broadcast
                if (e == 0xFFFF) continue;
                int row = (int)(e & 0xFFF);
                int c = scomp[row];
                const float* Drow = D + (size_t)row * N;
                u64 best = INFKEY;
                for (int j0 = lane * 4; j0 < N; j0 += 256) {
                    float4 d = *(const float4*)(Drow + j0);
                    int4 cj = *(const int4*)(scomp + j0);
                    if (cj.x != c) { u64 k = ((u64)__float_as_uint(d.x) << 12) | (unsigned)(j0 + 0); if (k < best) best = k; }
                    if (cj.y != c) { u64 k = ((u64)__float_as_uint(d.y) << 12) | (unsigned)(j0 + 1); if (k < best) best = k; }
                    if (cj.z != c) { u64 k = ((u64)__float_as_uint(d.z) << 12) | (unsigned)(j0 + 2); if (k < best) best = k; }
                    if (cj.w != c) { u64 k = ((u64)__float_as_uint(d.w) << 12) | (unsigned)(j0 + 3); if (k < best) best = k; }
                }
#pragma unroll
                for (int off = 32; off > 0; off >>= 1) {
                    u64 o = __shfl_xor(best, off, 64);
                    if (o < best) best = o;
                }
                if (lane == 0 && best != INFKEY) {
                    u64 key = ((best >> 12) << 24) | ((u64)row << 12) | (best & 0xFFF);
                    atomicMin(&gcand[c], key);
                }
            }
        }
        mat_barrier(bcnt, bgen, ++phase);   // B -> C

        // ---- phase C: leader hooks, records edges, compresses, writes back ----
        if (bm == 0) {
            for (int i = tid; i < N; i += 1024) scand[i] = gcand[i];   // stage final cand
            __syncthreads();
            u16* slink = sresc;
            for (int c = tid; c < N; c += 1024) {
                int l = scomp[c];
                if (l == c) {
                    u64 k = scand[c];
                    if (k != INFKEY) {
                        int v = (int)(k & 0xFFF);
                        int u = (int)((k >> 12) & 0xFFF);
                        int t = scomp[v];
                        u64 tk = scand[t];
                        int mutual = 0;
                        if (tk != INFKEY) {
                            int tv = (int)(tk & 0xFFF);
                            mutual = (scomp[tv] == c);
                        }
                        if (mutual) {
                            if (c < t) { int idx = atomicAdd(&secnt, 1); ged[idx] = make_int2(u, v); }
                            else l = t;
                        } else {
                            int idx = atomicAdd(&secnt, 1); ged[idx] = make_int2(u, v); l = t;
                        }
                    }
                }
                slink[c] = (u16)l;
            }
            __syncthreads();
            for (int c = tid; c < N; c += 1024) scomp[c] = slink[c];
            __syncthreads();
            for (int c = tid; c < N; c += 1024) {   // concurrent root-walk (monotone)
                int r = scomp[c];
                int n = scomp[r];
                while (n != r) { r = n; n = scomp[r]; }
                scomp[c] = r;
            }
            __syncthreads();
            if (tid == 0) scnt = 0;
            __syncthreads();
            int local = 0;
            for (int c = tid; c < N; c += 1024) local += (scomp[c] == c) ? 1 : 0;
            atomicAdd(&scnt, local);
            __syncthreads();
            if (tid == 0 && scnt == 1) *gdone = 1;           // release at barrier fence
            for (int i = tid; i < N / 4; i += 1024) ((int4*)gcomp)[i] = ((int4*)scomp)[i];
            for (int i = tid; i < N; i += 1024) gcand[i] = INFKEY;
        }
        mat_barrier(bcnt, bgen, ++phase);   // C -> next round
        if (__hip_atomic_load(gdone, __ATOMIC_RELAXED, __HIP_MEMORY_SCOPE_AGENT)) break;
    }

    if (bm != 0) return;

    // ================= Euler-tour rooting (leader block, depth-independent) ====
    u32* uvp  = (u32*)SM;                      // 16K @0
    u16* off  = (u16*)(SM + 16384);            // 8K
    u16* adj  = (u16*)(SM + 24576);            // 16K
    u16* succ = (u16*)(SM + 40960);            // 16K
    u16* rnk  = (u16*)(SM + 16384);            // aliases off+adj (dead)
    u32* minp = (u32*)(SM + 40960);            // aliases succ (dead)

    __syncthreads();
    const int ec = secnt;                      // == N-1
    for (int i = tid; i < ec; i += 1024) {
        int2 e = ged[i];
        uvp[i] = ((u32)e.x << 16) | (u32)e.y;
    }
    for (int i = tid; i < 2048; i += 1024) ((u32*)off)[i] = 0;
    __syncthreads();
    for (int i = tid; i < ec; i += 1024) {
        u32 w = uvp[i];
        int u = (int)(w >> 16), v = (int)(w & 0xFFFF);
        atomicAdd((u32*)off + (u >> 1), 1u << ((u & 1) * 16));
        atomicAdd((u32*)off + (v >> 1), 1u << ((v & 1) * 16));
    }
    __syncthreads();
    {
        const int i0 = tid * 4;
        int d0 = off[i0], d1 = off[i0 + 1], d2 = off[i0 + 2], d3 = off[i0 + 3];
        int t0 = d0, t01 = d0 + d1, t012 = t01 + d2, tot = t012 + d3;
        int inc = tot;
#pragma unroll
        for (int d = 1; d < 64; d <<= 1) {
            int o = __shfl_up(inc, d, 64);
            if (lane >= d) inc += o;
        }
        if (lane == 63) swar[wid] = inc;
        __syncthreads();
        if (wid == 0) {
            int v = (lane < 16) ? swar[lane] : 0;
            int vin = v;
#pragma unroll
            for (int d = 1; d < 16; d <<= 1) {
                int o = __shfl_up(v, d, 64);
                if (lane >= d) v += o;
            }
            if (lane < 16) swar[lane] = v - vin;
        }
        __syncthreads();
        int base = swar[wid] + (inc - tot);
        off[i0] = (u16)base;
        off[i0 + 1] = (u16)(base + t0);
        off[i0 + 2] = (u16)(base + t01);
        off[i0 + 3] = (u16)(base + t012);
    }
    __syncthreads();
    for (int e = tid; e < M2; e += 1024) {
        int i = e >> 1;
        u32 w = uvp[i];
        int src = (e & 1) ? (int)(w & 0xFFFF) : (int)(w >> 16);
        u32 old = atomicAdd((u32*)off + (src >> 1), 1u << ((src & 1) * 16));
        u32 slot = (old >> ((src & 1) * 16)) & 0xFFFFu;
        adj[slot] = (u16)e;
        succ[e] = (u16)slot;                 // temp: my slot
    }
    __syncthreads();
    const int e0 = adj[0];                   // first edge out of vertex 0 = tour start
    {
        u16 nsv[8];
        int k = 0;
        for (int e = tid; e < M2; e += 1024) {
            int i = e >> 1;
            u32 w = uvp[i];
            int v = (e & 1) ? (int)(w >> 16) : (int)(w & 0xFFFF);   // dst(e)
            int st = succ[e ^ 1];
            int start = (v == 0) ? 0 : off[v - 1];
            int end = off[v];
            int ns = (st + 1 < end) ? st + 1 : start;
            nsv[k++] = adj[ns];
        }
        __syncthreads();
        k = 0;
        for (int e = tid; e < M2; e += 1024) succ[e] = nsv[k++];
    }
    __syncthreads();
    for (int e = tid; e < M2; e += 1024) {
        u16 s = succ[e];
        if (s == (u16)e0) { succ[e] = (u16)e; rnk[e] = 0; }
        else rnk[e] = 1;
    }
    __syncthreads();
    for (int it = 0; it < 13; ++it) {
        u16 nr[8], s2[8];
        int k = 0;
        for (int e = tid; e < M2; e += 1024) {
            u16 s1 = succ[e];
            u16 r1 = rnk[e];
            nr[k] = (u16)(r1 + rnk[s1]);
            s2[k] = succ[s1];
            ++k;
        }
        __syncthreads();
        k = 0;
        for (int e = tid; e < M2; e += 1024) { rnk[e] = nr[k]; succ[e] = s2[k]; ++k; }
        __syncthreads();
    }
    for (int i = tid; i < N; i += 1024) minp[i] = 0xFFFFFFFFu;
    __syncthreads();
    for (int e = tid; e < M2; e += 1024) {
        int i = e >> 1;
        u32 w = uvp[i];
        int dst = (e & 1) ? (int)(w >> 16) : (int)(w & 0xFFFF);
        int srcv = (e & 1) ? (int)(w & 0xFFFF) : (int)(w >> 16);
        u32 p = (u32)(M2 - 1) - (u32)rnk[e];
        atomicMin(&minp[dst], (p << 16) | (u32)srcv);
    }
    __syncthreads();
    for (int v = tid; v < N; v += 1024) gpar[v] = (v == 0) ? 0 : (int)(minp[v] & 0xFFFFu);
}

__global__ __launch_bounds__(1024) void finalize_kernel(const float* __restrict__ D1,
                                                        const float* __restrict__ D2,
                                                        const int* __restrict__ parent,
                                                        float* __restrict__ out) {
    __shared__ float rs12[16], rs21[16];
    __shared__ int rm[16];
    const int tid = threadIdx.x;
    const int* p1 = parent;
    const int* p2 = parent + N;

    float s12 = 0.f, s21 = 0.f;
    int mcnt = 0;
    for (int c = 1 + tid; c < N; c += 1024) {
        int a = p1[c];
        int b = p2[c];
        float e1 = D1[(size_t)a * N + c] - D2[(size_t)a * N + c];
        float e2 = D2[(size_t)b * N + c] - D1[(size_t)b * N + c];
        s12 += e1 * e1;
        s21 += e2 * e2;
        mcnt += (a == b) ? 1 : 0;
    }
#pragma unroll
    for (int off = 32; off > 0; off >>= 1) {
        s12 += __shfl_xor(s12, off, 64);
        s21 += __shfl_xor(s21, off, 64);
        mcnt += __shfl_xor(mcnt, off, 64);
    }
    const int wid = tid >> 6, lane = tid & 63;
    if (lane == 0) { rs12[wid] = s12; rs21[wid] = s21; rm[wid] = mcnt; }
    __syncthreads();
    if (tid == 0) {
        float a = 0.f, b = 0.f;
        int mm = 0;
#pragma unroll
        for (int w = 0; w < 16; ++w) { a += rs12[w]; b += rs21[w]; mm += rm[w]; }
        float d12 = sqrtf(a);
        float d21 = sqrtf(b);
        out[0] = d12 + d21;
        out[1] = d12;
        out[2] = d21;
        out[3] = (float)mm;
    }
}

extern "C" void kernel_launch(void* const* d_in, const int* in_sizes, int n_in,
                              void* d_out, int out_size, void* d_ws, size_t ws_size,
                              hipStream_t stream) {
    const float* D1 = (const float*)d_in[0];
    const float* D2 = (const float*)d_in[1];

    int* parent = WS_PARENT(d_ws);
    int* rcnt = WS_RCNT(d_ws);
    float* rthr = WS_RTHR(d_ws);
    int2* edges = WS_EDGES(d_ws);
    int* comp = WS_COMP(d_ws);
    u64* cand = WS_CAND(d_ws);
    int* meta = WS_META(d_ws);
    u64* lists = WS_LISTS(d_ws);

    build_kernel<<<512, 1024, 0, stream>>>(D1, D2, rcnt, rthr, lists, comp, cand, meta);
    solve_kernel<<<2 * MBLK, 1024, 0, stream>>>(D1, D2, rcnt, rthr, lists, comp, cand,
                                                edges, parent, meta);
    finalize_kernel<<<1, 1024, 0, stream>>>(D1, D2, parent, (float*)d_out);
}

// Round 8
// 317.544 us; speedup vs baseline: 1.7609x; 1.0573x over previous
//
#include <hip/hip_runtime.h>
#include <math.h>

#define N 4096
#define ROUNDS 12           // components at least halve per round: 4096 -> 1 guaranteed
#define INFKEY 0xFFFFFFFFFFFFFFFFULL
#define LCAP 48             // candidate-list capacity per row (<= 64: one lane per entry)
#define EC (N - 1)          // MST edge count
#define M2 (2 * EC)         // directed edges (8190)
#define MBLK 32             // blocks per matrix
#define RPB (N / MBLK)      // 128 rows per block
#define RPW (RPB / 16)      // 8 rows per wave

typedef unsigned long long u64;
typedef unsigned int u32;
typedef unsigned short u16;

// ---- workspace layout (bytes) ----
#define WS_PARENT(ws) ((int*)((char*)(ws) + 0))          // int[2N]        32 KB
#define WS_RCNT(ws)   ((int*)((char*)(ws) + 32768))      // int[2N]        32 KB
#define WS_RTHR(ws)   ((float*)((char*)(ws) + 65536))    // float[2N]      32 KB
#define WS_EDGES(ws)  ((int2*)((char*)(ws) + 98304))     // int2[2N]       64 KB
#define WS_CAND(ws)   ((u64*)((char*)(ws) + 163840))     // u64[2][2N]    128 KB (double-buffered)
#define WS_META(ws)   ((int*)((char*)(ws) + 294912))     // int[64]
#define WS_LISTS(ws)  ((u64*)((char*)(ws) + 295168))     // u64[2N*LCAP]    3 MB, row-major

// cand key: (float_bits(w) << 24) | (u << 12) | v    (56 bits)
// list entry: (float_bits(w) << 12) | j              (44 bits)

// Per-matrix spin barrier over MBLK co-resident blocks (grid 64 on 256 CUs).
__device__ __forceinline__ void mat_barrier(int* cnt, int* gen, int target) {
    __syncthreads();
    if (threadIdx.x == 0) {
        __threadfence();
        int old = atomicAdd(cnt, 1);
        if (old == MBLK - 1) {
            __hip_atomic_store(cnt, 0, __ATOMIC_RELAXED, __HIP_MEMORY_SCOPE_AGENT);
            __hip_atomic_store(gen, target, __ATOMIC_RELEASE, __HIP_MEMORY_SCOPE_AGENT);
        } else {
            while (__hip_atomic_load(gen, __ATOMIC_ACQUIRE, __HIP_MEMORY_SCOPE_AGENT) < target)
                __builtin_amdgcn_s_sleep(1);
        }
        __threadfence();
    }
    __syncthreads();
}

// One wave per row, one full-matrix streaming pass. Threshold T = row min +
// 0.25*(mean-min), gap halved (register recount) until count <= LCAP: every
// row has a complete ball list AND a valid bound. Lists ROW-major. Folds init.
__global__ __launch_bounds__(1024) void build_kernel(const float* __restrict__ D1,
                                                     const float* __restrict__ D2,
                                                     int* __restrict__ rowcount,
                                                     float* __restrict__ rthresh,
                                                     u64* __restrict__ lists,
                                                     u64* __restrict__ cand,
                                                     int* __restrict__ meta) {
    const int gb = blockIdx.x;   // 512 blocks: 256 per matrix
    const int tid = threadIdx.x;

    // folded init (consumed only by the solve dispatch; kernel boundary orders it)
    if (gb < 4) {                                 // both cand buffers -> INFKEY (16384 u64)
        int i = (gb * 1024 + tid) * 4;
        cand[i] = INFKEY; cand[i + 1] = INFKEY; cand[i + 2] = INFKEY; cand[i + 3] = INFKEY;
    } else if (gb == 4 && tid < 64) {
        meta[tid] = 0;
    }

    const int m = gb >> 8;
    const int wid = tid >> 6, lane = tid & 63;
    const int row = (gb & 255) * 16 + wid;
    const float* __restrict__ Drow = (m ? D2 : D1) + (size_t)row * N;
    const float INF = __builtin_inff();

    float4 v[16];
#pragma unroll
    for (int it = 0; it < 16; ++it)
        v[it] = *(const float4*)(Drow + it * 256 + lane * 4);

    float mn = INF, sm = 0.f;
#pragma unroll
    for (int it = 0; it < 16; ++it) {
        float a = v[it].x, b = v[it].y, c = v[it].z, d = v[it].w;
        mn = fminf(mn, a > 0.f ? a : INF);   // excludes exact-zero diagonal
        mn = fminf(mn, b > 0.f ? b : INF);
        mn = fminf(mn, c > 0.f ? c : INF);
        mn = fminf(mn, d > 0.f ? d : INF);
        sm += a + b + c + d;                 // self adds 0, harmless
    }
#pragma unroll
    for (int off = 32; off > 0; off >>= 1) {
        mn = fminf(mn, __shfl_xor(mn, off, 64));
        sm += __shfl_xor(sm, off, 64);
    }
    const float mean = sm * (1.f / 4095.f);
    float T = mn + 0.25f * (mean - mn);

    int mycnt, total;
    for (int iter = 0; iter < 10; ++iter) {
        mycnt = 0;
#pragma unroll
        for (int it = 0; it < 16; ++it) {
            mycnt += (v[it].x > 0.f && v[it].x < T);
            mycnt += (v[it].y > 0.f && v[it].y < T);
            mycnt += (v[it].z > 0.f && v[it].z < T);
            mycnt += (v[it].w > 0.f && v[it].w < T);
        }
        total = mycnt;
#pragma unroll
        for (int off = 32; off > 0; off >>= 1) total += __shfl_xor(total, off, 64);
        if (total <= LCAP) break;
        T = mn + 0.5f * (T - mn);
    }

    int incl = mycnt;
#pragma unroll
    for (int d = 1; d < 64; d <<= 1) {
        int o = __shfl_up(incl, d, 64);
        if (lane >= d) incl += o;
    }
    int pos = incl - mycnt;

    u64* lp = lists + ((size_t)m * N + row) * LCAP;   // ROW-major
#pragma unroll
    for (int it = 0; it < 16; ++it) {
        float e4[4] = {v[it].x, v[it].y, v[it].z, v[it].w};
#pragma unroll
        for (int s = 0; s < 4; ++s) {
            float x = e4[s];
            if (x > 0.f && x < T) {
                if (pos < LCAP)
                    lp[pos] = ((u64)__float_as_uint(x) << 12) | (unsigned)(it * 256 + lane * 4 + s);
                ++pos;
            }
        }
    }
    if (lane == 0) {
        rowcount[m * N + row] = total;
        rthresh[m * N + row] = T;
    }
}

// 32 blocks per matrix (64 total). Leaderless rounds: every block keeps a
// private full comp in LDS and redundantly computes hook+compress from the
// (identical) quiescent global cand -- no leader serialization, 2 barriers
// per round (double-buffered cand). Leaders do Euler-tour rooting; block 0
// then computes the final outputs (fused finalize).
__global__ __launch_bounds__(1024) void solve_kernel(const float* __restrict__ D1,
                                                     const float* __restrict__ D2,
                                                     const int* __restrict__ rcnt,
                                                     const float* __restrict__ rthr,
                                                     const u64* __restrict__ lists,
                                                     u64* __restrict__ cand_g,
                                                     int2* __restrict__ edges_g,
                                                     int* __restrict__ parent_g,
                                                     int* __restrict__ meta,
                                                     float* __restrict__ out) {
    const int b = blockIdx.x;
    const int m = b / MBLK;
    const int bm = b - m * MBLK;
    const int tid = threadIdx.x;
    const int wid = tid >> 6, lane = tid & 63;
    const float* __restrict__ D = m ? D2 : D1;
    const int* __restrict__ grc = rcnt + m * N;
    const float* __restrict__ gth = rthr + m * N;
    const u64* __restrict__ gls = lists + (size_t)m * N * LCAP;
    int2* __restrict__ ged = edges_g + (size_t)m * N;
    int* __restrict__ gpar = parent_g + m * N;
    int* bcnt = meta + m * 16 + 1;
    int* bgen = meta + m * 16 + 2;
    int* garr = meta + 40;                 // global arrive counter (all 64 blocks)
    const float INF = __builtin_inff();

    __shared__ __align__(16) char SM[57344];   // 56 KB arena, phase-aliased
    int* scomp = (int*)SM;                     // 16 KB @0   (private full comp)
    u64* scand = (u64*)(SM + 16384);           // 32 KB @16K (local min mirror / staged cand)
    u16* sresc = (u16*)(SM + 49152);           // 8 KB  @48K (rescan list / slink)
    __shared__ int snres, secnt, scnt, swar[16];

    for (int i = tid; i < N; i += 1024) scomp[i] = i;
    if (tid == 0) secnt = 0;
    int phase = 0;
    bool done = false;

    for (int round = 0; round < ROUNDS && !done; ++round) {
        const int buf = round & 1;
        u64* __restrict__ gcand = cand_g + (size_t)buf * 2 * N + m * N;
        u64* __restrict__ gcand_o = cand_g + (size_t)(buf ^ 1) * 2 * N + m * N;

        for (int i = tid; i < N; i += 1024) scand[i] = INFKEY;
        if (tid == 0) snres = 0;
        __syncthreads();

        // ---- phase A: list scan, wave-per-row, lane-per-entry; block-local min ----
        for (int r = 0; r < RPW; ++r) {
            const int row = bm * RPB + wid * RPW + r;
            const int c = scomp[row];
            const int cnt = grc[row];
            const bool forced = (cnt > LCAP);   // defensive; empty after adaptive build
            u64 best = INFKEY;
            if (!forced && lane < cnt) {
                u64 e = gls[(size_t)row * LCAP + lane];
                int j = (int)(e & 0xFFF);
                if (scomp[j] != c) best = e;
            }
#pragma unroll
            for (int off = 32; off > 0; off >>= 1) {
                u64 o = __shfl_xor(best, off, 64);
                if (o < best) best = o;
            }
            if (lane == 0) {
                if (best != INFKEY) {
                    u64 key = ((best >> 12) << 24) | ((u64)row << 12) | (best & 0xFFF);
                    if (key < scand[c]) atomicMin(&scand[c], key);   // LDS, guarded
                } else {
                    int i = atomicAdd(&snres, 1);
                    sresc[i] = (u16)(row | (forced ? 0x4000 : 0x1000));
                }
            }
        }
        __syncthreads();
        // flush block-local mins to global (<=128 atomics, <=32-way contention)
        for (int c = tid; c < N; c += 1024) {
            u64 v = scand[c];
            if (v != INFKEY) atomicMin(&gcand[c], v);
        }
        mat_barrier(bcnt, bgen, ++phase);   // A -> B

        // ---- phase B: bound filter + rare rescans; reset idle cand buffer slice ----
        for (int i = tid + bm * 0; i < RPB; i += 1024)
            if (tid < RPB) gcand_o[bm * RPB + tid] = INFKEY;   // one slice per block
        for (int i = tid; i < snres; i += 1024) {
            u16 e = sresc[i];
            if (e & 0x1000) {
                int row = e & 0xFFF;
                int c = scomp[row];
                u64 cc = gcand[c];               // monotone-decreasing: skip stays safe
                float w = (cc == INFKEY) ? INF : __uint_as_float((u32)(cc >> 24));
                if (!(gth[row] < w)) sresc[i] = 0xFFFF;
            }
        }
        __syncthreads();
        {
            const int nres = snres;
            for (int i = wid; i < nres; i += 16) {
                u16 e = sresc[i];                // wave-uniform broadcast
                if (e == 0xFFFF) continue;
                int row = (int)(e & 0xFFF);
                int c = scomp[row];
                const float* Drow = D + (size_t)row * N;
                u64 best = INFKEY;
                for (int j0 = lane * 4; j0 < N; j0 += 256) {
                    float4 d = *(const float4*)(Drow + j0);
                    int4 cj = *(const int4*)(scomp + j0);
                    if (cj.x != c) { u64 k = ((u64)__float_as_uint(d.x) << 12) | (unsigned)(j0 + 0); if (k < best) best = k; }
                    if (cj.y != c) { u64 k = ((u64)__float_as_uint(d.y) << 12) | (unsigned)(j0 + 1); if (k < best) best = k; }
                    if (cj.z != c) { u64 k = ((u64)__float_as_uint(d.z) << 12) | (unsigned)(j0 + 2); if (k < best) best = k; }
                    if (cj.w != c) { u64 k = ((u64)__float_as_uint(d.w) << 12) | (unsigned)(j0 + 3); if (k < best) best = k; }
                }
#pragma unroll
                for (int off = 32; off > 0; off >>= 1) {
                    u64 o = __shfl_xor(best, off, 64);
                    if (o < best) best = o;
                }
                if (lane == 0 && best != INFKEY) {
                    u64 key = ((best >> 12) << 24) | ((u64)row << 12) | (best & 0xFFF);
                    atomicMin(&gcand[c], key);
                }
            }
        }
        mat_barrier(bcnt, bgen, ++phase);   // B -> C

        // ---- phase C (all blocks, redundant+deterministic): stage cand, hook,
        //      record edges (block 0 only), compress, done check ----
        for (int i = tid; i < N; i += 1024) scand[i] = gcand[i];   // quiescent post-barrier
        __syncthreads();
        u16* slink = sresc;
        for (int c = tid; c < N; c += 1024) {
            int l = scomp[c];
            if (l == c) {
                u64 k = scand[c];
                if (k != INFKEY) {
                    int v = (int)(k & 0xFFF);
                    int u = (int)((k >> 12) & 0xFFF);
                    int t = scomp[v];
                    u64 tk = scand[t];
                    int mutual = 0;
                    if (tk != INFKEY) {
                        int tv = (int)(tk & 0xFFF);
                        mutual = (scomp[tv] == c);
                    }
                    if (mutual) {
                        if (c < t) {
                            if (bm == 0) { int idx = atomicAdd(&secnt, 1); ged[idx] = make_int2(u, v); }
                        } else l = t;
                    } else {
                        if (bm == 0) { int idx = atomicAdd(&secnt, 1); ged[idx] = make_int2(u, v); }
                        l = t;
                    }
                }
            }
            slink[c] = (u16)l;
        }
        __syncthreads();
        for (int c = tid; c < N; c += 1024) scomp[c] = slink[c];
        __syncthreads();
        for (int c = tid; c < N; c += 1024) {   // concurrent root-walk (monotone)
            int r = scomp[c];
            int n = scomp[r];
            while (n != r) { r = n; n = scomp[r]; }
            scomp[c] = r;
        }
        __syncthreads();
        if (tid == 0) scnt = 0;
        __syncthreads();
        int local = 0;
        for (int c = tid; c < N; c += 1024) local += (scomp[c] == c) ? 1 : 0;
        atomicAdd(&scnt, local);
        __syncthreads();
        done = (scnt == 1);                  // identical across blocks
        __syncthreads();
    }

    if (bm == 0) {
        // ============ Euler-tour rooting (leader block, depth-independent) =====
        u32* uvp  = (u32*)SM;                      // 16K @0
        u16* off  = (u16*)(SM + 16384);            // 8K
        u16* adj  = (u16*)(SM + 24576);            // 16K
        u16* succ = (u16*)(SM + 40960);            // 16K
        u16* rnk  = (u16*)(SM + 16384);            // aliases off+adj (dead)
        u32* minp = (u32*)(SM + 40960);            // aliases succ (dead)

        __syncthreads();
        const int ec = secnt;                      // == N-1
        for (int i = tid; i < ec; i += 1024) {
            int2 e = ged[i];
            uvp[i] = ((u32)e.x << 16) | (u32)e.y;
        }
        for (int i = tid; i < 2048; i += 1024) ((u32*)off)[i] = 0;
        __syncthreads();
        for (int i = tid; i < ec; i += 1024) {
            u32 w = uvp[i];
            int u = (int)(w >> 16), v = (int)(w & 0xFFFF);
            atomicAdd((u32*)off + (u >> 1), 1u << ((u & 1) * 16));
            atomicAdd((u32*)off + (v >> 1), 1u << ((v & 1) * 16));
        }
        __syncthreads();
        {
            const int i0 = tid * 4;
            int d0 = off[i0], d1 = off[i0 + 1], d2 = off[i0 + 2], d3 = off[i0 + 3];
            int t0 = d0, t01 = d0 + d1, t012 = t01 + d2, tot = t012 + d3;
            int inc = tot;
#pragma unroll
            for (int d = 1; d < 64; d <<= 1) {
                int o = __shfl_up(inc, d, 64);
                if (lane >= d) inc += o;
            }
            if (lane == 63) swar[wid] = inc;
            __syncthreads();
            if (wid == 0) {
                int v = (lane < 16) ? swar[lane] : 0;
                int vin = v;
#pragma unroll
                for (int d = 1; d < 16; d <<= 1) {
                    int o = __shfl_up(v, d, 64);
                    if (lane >= d) v += o;
                }
                if (lane < 16) swar[lane] = v - vin;
            }
            __syncthreads();
            int base = swar[wid] + (inc - tot);
            off[i0] = (u16)base;
            off[i0 + 1] = (u16)(base + t0);
            off[i0 + 2] = (u16)(base + t01);
            off[i0 + 3] = (u16)(base + t012);
        }
        __syncthreads();
        for (int e = tid; e < M2; e += 1024) {
            int i = e >> 1;
            u32 w = uvp[i];
            int src = (e & 1) ? (int)(w & 0xFFFF) : (int)(w >> 16);
            u32 old = atomicAdd((u32*)off + (src >> 1), 1u << ((src & 1) * 16));
            u32 slot = (old >> ((src & 1) * 16)) & 0xFFFFu;
            adj[slot] = (u16)e;
            succ[e] = (u16)slot;                 // temp: my slot
        }
        __syncthreads();
        const int e0 = adj[0];                   // first edge out of vertex 0 = tour start
        {
            u16 nsv[8];
            int k = 0;
            for (int e = tid; e < M2; e += 1024) {
                int i = e >> 1;
                u32 w = uvp[i];
                int v = (e & 1) ? (int)(w >> 16) : (int)(w & 0xFFFF);   // dst(e)
                int st = succ[e ^ 1];
                int start = (v == 0) ? 0 : off[v - 1];
                int end = off[v];
                int ns = (st + 1 < end) ? st + 1 : start;
                nsv[k++] = adj[ns];
            }
            __syncthreads();
            k = 0;
            for (int e = tid; e < M2; e += 1024) succ[e] = nsv[k++];
        }
        __syncthreads();
        for (int e = tid; e < M2; e += 1024) {
            u16 s = succ[e];
            if (s == (u16)e0) { succ[e] = (u16)e; rnk[e] = 0; }
            else rnk[e] = 1;
        }
        __syncthreads();
        for (int it = 0; it < 13; ++it) {
            u16 nr[8], s2[8];
            int k = 0;
            for (int e = tid; e < M2; e += 1024) {
                u16 s1 = succ[e];
                u16 r1 = rnk[e];
                nr[k] = (u16)(r1 + rnk[s1]);
                s2[k] = succ[s1];
                ++k;
            }
            __syncthreads();
            k = 0;
            for (int e = tid; e < M2; e += 1024) { rnk[e] = nr[k]; succ[e] = s2[k]; ++k; }
            __syncthreads();
        }
        for (int i = tid; i < N; i += 1024) minp[i] = 0xFFFFFFFFu;
        __syncthreads();
        for (int e = tid; e < M2; e += 1024) {
            int i = e >> 1;
            u32 w = uvp[i];
            int dst = (e & 1) ? (int)(w >> 16) : (int)(w & 0xFFFF);
            int srcv = (e & 1) ? (int)(w & 0xFFFF) : (int)(w >> 16);
            u32 p = (u32)(M2 - 1) - (u32)rnk[e];
            atomicMin(&minp[dst], (p << 16) | (u32)srcv);
        }
        __syncthreads();
        for (int v = tid; v < N; v += 1024) gpar[v] = (v == 0) ? 0 : (int)(minp[v] & 0xFFFFu);
    }

    // ---- global arrive; block 0 waits for all 64, then computes outputs ----
    __syncthreads();
    if (tid == 0) {
        __threadfence();
        atomicAdd(garr, 1);
    }
    if (b != 0) return;
    if (tid == 0) {
        while (__hip_atomic_load(garr, __ATOMIC_ACQUIRE, __HIP_MEMORY_SCOPE_AGENT) < 64)
            __builtin_amdgcn_s_sleep(1);
        __threadfence();
    }
    __syncthreads();

    // fused finalize (block 0 only)
    {
        float* rs12 = (float*)SM;            // tiny scratch
        float* rs21 = (float*)(SM + 64);
        int* rm = (int*)(SM + 128);
        const int* p1 = parent_g;
        const int* p2 = parent_g + N;
        float s12 = 0.f, s21 = 0.f;
        int mcnt = 0;
        for (int c = 1 + tid; c < N; c += 1024) {
            int a = p1[c];
            int bb = p2[c];
            float e1 = D1[(size_t)a * N + c] - D2[(size_t)a * N + c];
            float e2 = D2[(size_t)bb * N + c] - D1[(size_t)bb * N + c];
            s12 += e1 * e1;
            s21 += e2 * e2;
            mcnt += (a == bb) ? 1 : 0;
        }
#pragma unroll
        for (int off = 32; off > 0; off >>= 1) {
            s12 += __shfl_xor(s12, off, 64);
            s21 += __shfl_xor(s21, off, 64);
            mcnt += __shfl_xor(mcnt, off, 64);
        }
        if (lane == 0) { rs12[wid] = s12; rs21[wid] = s21; rm[wid] = mcnt; }
        __syncthreads();
        if (tid == 0) {
            float a = 0.f, bb = 0.f;
            int mm = 0;
#pragma unroll
            for (int w = 0; w < 16; ++w) { a += rs12[w]; bb += rs21[w]; mm += rm[w]; }
            float d12 = sqrtf(a);
            float d21 = sqrtf(bb);
            out[0] = d12 + d21;
            out[1] = d12;
            out[2] = d21;
            out[3] = (float)mm;
        }
    }
}

extern "C" void kernel_launch(void* const* d_in, const int* in_sizes, int n_in,
                              void* d_out, int out_size, void* d_ws, size_t ws_size,
                              hipStream_t stream) {
    const float* D1 = (const float*)d_in[0];
    const float* D2 = (const float*)d_in[1];

    int* parent = WS_PARENT(d_ws);
    int* rcnt = WS_RCNT(d_ws);
    float* rthr = WS_RTHR(d_ws);
    int2* edges = WS_EDGES(d_ws);
    u64* cand = WS_CAND(d_ws);
    int* meta = WS_META(d_ws);
    u64* lists = WS_LISTS(d_ws);

    build_kernel<<<512, 1024, 0, stream>>>(D1, D2, rcnt, rthr, lists, cand, meta);
    solve_kernel<<<2 * MBLK, 1024, 0, stream>>>(D1, D2, rcnt, rthr, lists, cand,
                                                edges, parent, meta, (float*)d_out);
}

// Round 9
// 309.118 us; speedup vs baseline: 1.8089x; 1.0273x over previous
//
#include <hip/hip_runtime.h>
#include <math.h>

#define N 4096
#define ROUNDS 12           // round 0 (folded) + 11: components at least halve per hook
#define INFKEY 0xFFFFFFFFFFFFFFFFULL
#define LCAP 64             // candidate-list capacity per row == wave width
#define EC (N - 1)          // MST edge count
#define M2 (2 * EC)         // directed edges (8190)
#define MBLK 32             // blocks per matrix
#define RPB (N / MBLK)      // 128 rows per block
#define RPW (RPB / 16)      // 8 rows per wave

typedef unsigned long long u64;
typedef unsigned int u32;
typedef unsigned short u16;
typedef unsigned char u8;

// ---- workspace layout (bytes) ----
#define WS_PARENT(ws) ((int*)((char*)(ws) + 0))          // int[2N]        32 KB
#define WS_RCNT(ws)   ((int*)((char*)(ws) + 32768))      // int[2N]        32 KB
#define WS_RTHR(ws)   ((float*)((char*)(ws) + 65536))    // float[2N]      32 KB
#define WS_EDGES(ws)  ((int2*)((char*)(ws) + 98304))     // int2[2N]       64 KB
#define WS_CAND(ws)   ((u64*)((char*)(ws) + 163840))     // u64[2][2N]    128 KB (double-buffered)
#define WS_META(ws)   ((int*)((char*)(ws) + 294912))     // int[64]
#define WS_LISTS(ws)  ((u64*)((char*)(ws) + 295168))     // u64[2N*LCAP]    4 MB, row-major

// cand key: (float_bits(w) << 24) | (u << 12) | v    (56 bits)
// list entry: (float_bits(w) << 12) | j              (44 bits)

// Per-matrix spin barrier over MBLK co-resident blocks (grid 64 on 256 CUs).
__device__ __forceinline__ void mat_barrier(int* cnt, int* gen, int target) {
    __syncthreads();
    if (threadIdx.x == 0) {
        __threadfence();
        int old = atomicAdd(cnt, 1);
        if (old == MBLK - 1) {
            __hip_atomic_store(cnt, 0, __ATOMIC_RELAXED, __HIP_MEMORY_SCOPE_AGENT);
            __hip_atomic_store(gen, target, __ATOMIC_RELEASE, __HIP_MEMORY_SCOPE_AGENT);
        } else {
            while (__hip_atomic_load(gen, __ATOMIC_ACQUIRE, __HIP_MEMORY_SCOPE_AGENT) < target)
                __builtin_amdgcn_s_sleep(1);
        }
        __threadfence();
    }
    __syncthreads();
}

// One wave per row, one full-matrix streaming pass. Computes (a) the row-min
// KEY (weight<<12 | argmin) -> written straight into cand buffer 0 = Boruvka
// round 1, done for free; (b) adaptive ball threshold T (gap halved until
// count <= LCAP) and the row's complete ball list (ROW-major).
__global__ __launch_bounds__(1024) void build_kernel(const float* __restrict__ D1,
                                                     const float* __restrict__ D2,
                                                     int* __restrict__ rowcount,
                                                     float* __restrict__ rthresh,
                                                     u64* __restrict__ lists,
                                                     u64* __restrict__ cand,
                                                     int* __restrict__ meta) {
    const int gb = blockIdx.x;   // 512 blocks: 256 per matrix
    const int tid = threadIdx.x;

    // folded init: only cand buffer 1 (buffer 0 is fully written below) + meta
    if (gb < 2) {
        int i = 2 * N + (gb * 1024 + tid) * 4;
        cand[i] = INFKEY; cand[i + 1] = INFKEY; cand[i + 2] = INFKEY; cand[i + 3] = INFKEY;
    } else if (gb == 2 && tid < 64) {
        meta[tid] = 0;
    }

    const int m = gb >> 8;
    const int wid = tid >> 6, lane = tid & 63;
    const int row = (gb & 255) * 16 + wid;
    const float* __restrict__ Drow = (m ? D2 : D1) + (size_t)row * N;
    const float INF = __builtin_inff();

    float4 v[16];
#pragma unroll
    for (int it = 0; it < 16; ++it)
        v[it] = *(const float4*)(Drow + it * 256 + lane * 4);

    // row-min KEY (weight bits << 12 | index) + sum, one reduce
    u64 kmin = INFKEY;
    float sm = 0.f;
#pragma unroll
    for (int it = 0; it < 16; ++it) {
        float e4[4] = {v[it].x, v[it].y, v[it].z, v[it].w};
#pragma unroll
        for (int s = 0; s < 4; ++s) {
            float x = e4[s];
            if (x > 0.f) {   // excludes exact-zero diagonal
                u64 k = ((u64)__float_as_uint(x) << 12) | (unsigned)(it * 256 + lane * 4 + s);
                if (k < kmin) kmin = k;
            }
            sm += x;         // self adds 0, harmless
        }
    }
#pragma unroll
    for (int off = 32; off > 0; off >>= 1) {
        u64 o = __shfl_xor(kmin, off, 64);
        if (o < kmin) kmin = o;
        sm += __shfl_xor(sm, off, 64);
    }
    const float mn = __uint_as_float((u32)(kmin >> 12));
    const float mean = sm * (1.f / 4095.f);
    float T = mn + 0.25f * (mean - mn);

    int mycnt, total;
    for (int iter = 0; iter < 10; ++iter) {
        mycnt = 0;
#pragma unroll
        for (int it = 0; it < 16; ++it) {
            mycnt += (v[it].x > 0.f && v[it].x < T);
            mycnt += (v[it].y > 0.f && v[it].y < T);
            mycnt += (v[it].z > 0.f && v[it].z < T);
            mycnt += (v[it].w > 0.f && v[it].w < T);
        }
        total = mycnt;
#pragma unroll
        for (int off = 32; off > 0; off >>= 1) total += __shfl_xor(total, off, 64);
        if (total <= LCAP) break;
        T = mn + 0.5f * (T - mn);
    }

    int incl = mycnt;
#pragma unroll
    for (int d = 1; d < 64; d <<= 1) {
        int o = __shfl_up(incl, d, 64);
        if (lane >= d) incl += o;
    }
    int pos = incl - mycnt;

    u64* lp = lists + ((size_t)m * N + row) * LCAP;   // ROW-major
#pragma unroll
    for (int it = 0; it < 16; ++it) {
        float e4[4] = {v[it].x, v[it].y, v[it].z, v[it].w};
#pragma unroll
        for (int s = 0; s < 4; ++s) {
            float x = e4[s];
            if (x > 0.f && x < T) {
                if (pos < LCAP)
                    lp[pos] = ((u64)__float_as_uint(x) << 12) | (unsigned)(it * 256 + lane * 4 + s);
                ++pos;
            }
        }
    }
    if (lane == 0) {
        rowcount[m * N + row] = total;
        rthresh[m * N + row] = T;
        // Boruvka round-1 candidate: every vertex its own component, unique writer
        cand[m * N + row] = ((kmin >> 12) << 24) | ((u64)row << 12) | (kmin & 0xFFF);
    }
}

// 32 blocks per matrix (64 total). Round 0 = hook only (cand from build, no
// barriers). Rounds 1+: A (prefetched list scan, exhausted rows skipped
// permanently) -> barrier -> B (bound filter + rare rescans, reset idle cand
// buffer) -> barrier -> C (redundant deterministic hook+compress, block 0
// records edges). Leaders then do Euler-tour rooting; block 0 fuses finalize.
__global__ __launch_bounds__(1024) void solve_kernel(const float* __restrict__ D1,
                                                     const float* __restrict__ D2,
                                                     const int* __restrict__ rcnt,
                                                     const float* __restrict__ rthr,
                                                     const u64* __restrict__ lists,
                                                     u64* __restrict__ cand_g,
                                                     int2* __restrict__ edges_g,
                                                     int* __restrict__ parent_g,
                                                     int* __restrict__ meta,
                                                     float* __restrict__ out) {
    const int b = blockIdx.x;
    const int m = b / MBLK;
    const int bm = b - m * MBLK;
    const int tid = threadIdx.x;
    const int wid = tid >> 6, lane = tid & 63;
    const float* __restrict__ D = m ? D2 : D1;
    const int* __restrict__ grc = rcnt + m * N;
    const float* __restrict__ gth = rthr + m * N;
    const u64* __restrict__ gls = lists + (size_t)m * N * LCAP;
    int2* __restrict__ ged = edges_g + (size_t)m * N;
    int* __restrict__ gpar = parent_g + m * N;
    int* bcnt = meta + m * 16 + 1;
    int* bgen = meta + m * 16 + 2;
    int* garr = meta + 40;                 // global arrive counter (all 64 blocks)
    const float INF = __builtin_inff();

    __shared__ __align__(16) char SM[57344];   // 56 KB arena, phase-aliased
    int* scomp = (int*)SM;                     // 16 KB @0   (private full comp)
    u64* scand = (u64*)(SM + 16384);           // 32 KB @16K (local min mirror / staged cand)
    u16* sresc = (u16*)(SM + 49152);           // 8 KB  @48K (rescan list / slink)
    __shared__ u8 sexh[RPB];                   // monotone exhausted-row flags
    __shared__ int snres, secnt, scnt, swar[16];

    for (int i = tid; i < N; i += 1024) scomp[i] = i;
    for (int i = tid; i < RPB; i += 1024) sexh[i] = 0;
    if (tid == 0) secnt = 0;
    int phase = 0;
    bool done = false;

    for (int round = 0; round < ROUNDS && !done; ++round) {
        const int buf = round & 1;
        u64* __restrict__ gcand = cand_g + (size_t)buf * 2 * N + m * N;

        if (round > 0) {
            u64* __restrict__ gcand_o = cand_g + (size_t)(buf ^ 1) * 2 * N + m * N;
            for (int i = tid; i < N; i += 1024) scand[i] = INFKEY;
            if (tid == 0) snres = 0;
            __syncthreads();

            // ---- phase A: prefetched list scan; exhausted rows skip ----
            {
                const int lbase = wid * RPW;
                int cnts[RPW];
                u64 ent[RPW];
#pragma unroll
                for (int r = 0; r < RPW; ++r) {
                    int lrow = lbase + r;
                    cnts[r] = sexh[lrow] ? -1 : grc[bm * RPB + lrow];   // uniform scalar load
                }
#pragma unroll
                for (int r = 0; r < RPW; ++r) {   // 8 independent global loads in flight
                    int lrow = lbase + r;
                    ent[r] = (cnts[r] > lane) ? gls[(size_t)(bm * RPB + lrow) * LCAP + lane]
                                              : INFKEY;
                }
#pragma unroll
                for (int r = 0; r < RPW; ++r) {
                    const int lrow = lbase + r;
                    const int row = bm * RPB + lrow;
                    if (cnts[r] < 0) {                       // known exhausted
                        if (lane == 0) { int i = atomicAdd(&snres, 1); sresc[i] = (u16)(row | 0x1000); }
                        continue;
                    }
                    if (cnts[r] > LCAP) {                    // defensive overflow
                        if (lane == 0) { int i = atomicAdd(&snres, 1); sresc[i] = (u16)(row | 0x4000); }
                        continue;
                    }
                    const int c = scomp[row];
                    u64 e = ent[r];
                    u64 best = (e != INFKEY && scomp[(int)(e & 0xFFF)] != c) ? e : INFKEY;
#pragma unroll
                    for (int off = 32; off > 0; off >>= 1) {
                        u64 o = __shfl_xor(best, off, 64);
                        if (o < best) best = o;
                    }
                    if (lane == 0) {
                        if (best != INFKEY) {
                            u64 key = ((best >> 12) << 24) | ((u64)row << 12) | (best & 0xFFF);
                            if (key < scand[c]) atomicMin(&scand[c], key);
                        } else {
                            sexh[lrow] = 1;                  // permanent (monotone)
                            int i = atomicAdd(&snres, 1); sresc[i] = (u16)(row | 0x1000);
                        }
                    }
                }
            }
            __syncthreads();
            for (int c = tid; c < N; c += 1024) {            // flush block-local mins
                u64 v = scand[c];
                if (v != INFKEY) atomicMin(&gcand[c], v);
            }
            mat_barrier(bcnt, bgen, ++phase);   // A -> B

            // ---- phase B: reset idle buffer slice; bound filter; rare rescans ----
            if (tid < RPB)
                __hip_atomic_store(&gcand_o[bm * RPB + tid], INFKEY,
                                   __ATOMIC_RELAXED, __HIP_MEMORY_SCOPE_AGENT);
            for (int i = tid; i < snres; i += 1024) {
                u16 e = sresc[i];
                if (e & 0x1000) {
                    int row = e & 0xFFF;
                    int c = scomp[row];
                    u64 cc = gcand[c];           // monotone-decreasing: skip stays safe
                    float w = (cc == INFKEY) ? INF : __uint_as_float((u32)(cc >> 24));
                    if (!(gth[row] < w)) sresc[i] = 0xFFFF;
                }
            }
            __syncthreads();
            {
                const int nres = snres;
                for (int i = wid; i < nres; i += 16) {
                    u16 e = sresc[i];            // wave-uniform broadcast
                    if (e == 0xFFFF) continue;
                    int row = (int)(e & 0xFFF);
                    int c = scomp[row];
                    const float* Drow = D + (size_t)row * N;
                    u64 best = INFKEY;
                    for (int j0 = lane * 4; j0 < N; j0 += 256) {
                        float4 d = *(const float4*)(Drow + j0);
                        int4 cj = *(const int4*)(scomp + j0);
                        if (cj.x != c) { u64 k = ((u64)__float_as_uint(d.x) << 12) | (unsigned)(j0 + 0); if (k < best) best = k; }
                        if (cj.y != c) { u64 k = ((u64)__float_as_uint(d.y) << 12) | (unsigned)(j0 + 1); if (k < best) best = k; }
                        if (cj.z != c) { u64 k = ((u64)__float_as_uint(d.z) << 12) | (unsigned)(j0 + 2); if (k < best) best = k; }
                        if (cj.w != c) { u64 k = ((u64)__float_as_uint(d.w) << 12) | (unsigned)(j0 + 3); if (k < best) best = k; }
                    }
#pragma unroll
                    for (int off = 32; off > 0; off >>= 1) {
                        u64 o = __shfl_xor(best, off, 64);
                        if (o < best) best = o;
                    }
                    if (lane == 0 && best != INFKEY) {
                        u64 key = ((best >> 12) << 24) | ((u64)row << 12) | (best & 0xFFF);
                        atomicMin(&gcand[c], key);
                    }
                }
            }
            mat_barrier(bcnt, bgen, ++phase);   // B -> C
        }

        // ---- phase C (all blocks, redundant+deterministic): stage cand, hook,
        //      record edges (block 0 only), compress, done check ----
        for (int i = tid; i < N; i += 1024) scand[i] = gcand[i];   // quiescent
        __syncthreads();
        u16* slink = sresc;
        for (int c = tid; c < N; c += 1024) {
            int l = scomp[c];
            if (l == c) {
                u64 k = scand[c];
                if (k != INFKEY) {
                    int v = (int)(k & 0xFFF);
                    int u = (int)((k >> 12) & 0xFFF);
                    int t = scomp[v];
                    u64 tk = scand[t];
                    int mutual = 0;
                    if (tk != INFKEY) {
                        int tv = (int)(tk & 0xFFF);
                        mutual = (scomp[tv] == c);
                    }
                    if (mutual) {
                        if (c < t) {
                            if (bm == 0) { int idx = atomicAdd(&secnt, 1); ged[idx] = make_int2(u, v); }
                        } else l = t;
                    } else {
                        if (bm == 0) { int idx = atomicAdd(&secnt, 1); ged[idx] = make_int2(u, v); }
                        l = t;
                    }
                }
            }
            slink[c] = (u16)l;
        }
        __syncthreads();
        for (int c = tid; c < N; c += 1024) scomp[c] = slink[c];
        __syncthreads();
        for (int c = tid; c < N; c += 1024) {   // concurrent root-walk (monotone)
            int r = scomp[c];
            int n = scomp[r];
            while (n != r) { r = n; n = scomp[r]; }
            scomp[c] = r;
        }
        __syncthreads();
        if (tid == 0) scnt = 0;
        __syncthreads();
        int local = 0;
        for (int c = tid; c < N; c += 1024) local += (scomp[c] == c) ? 1 : 0;
        atomicAdd(&scnt, local);
        __syncthreads();
        done = (scnt == 1);                  // identical across blocks
        __syncthreads();
    }

    if (bm == 0) {
        // ============ Euler-tour rooting (leader block, depth-independent) =====
        u32* uvp  = (u32*)SM;                      // 16K @0
        u16* off  = (u16*)(SM + 16384);            // 8K
        u16* adj  = (u16*)(SM + 24576);            // 16K
        u16* succ = (u16*)(SM + 40960);            // 16K
        u16* rnk  = (u16*)(SM + 16384);            // aliases off+adj (dead)
        u32* minp = (u32*)(SM + 40960);            // aliases succ (dead)

        __syncthreads();
        const int ec = secnt;                      // == N-1
        for (int i = tid; i < ec; i += 1024) {
            int2 e = ged[i];
            uvp[i] = ((u32)e.x << 16) | (u32)e.y;
        }
        for (int i = tid; i < 2048; i += 1024) ((u32*)off)[i] = 0;
        __syncthreads();
        for (int i = tid; i < ec; i += 1024) {
            u32 w = uvp[i];
            int u = (int)(w >> 16), v = (int)(w & 0xFFFF);
            atomicAdd((u32*)off + (u >> 1), 1u << ((u & 1) * 16));
            atomicAdd((u32*)off + (v >> 1), 1u << ((v & 1) * 16));
        }
        __syncthreads();
        {
            const int i0 = tid * 4;
            int d0 = off[i0], d1 = off[i0 + 1], d2 = off[i0 + 2], d3 = off[i0 + 3];
            int t0 = d0, t01 = d0 + d1, t012 = t01 + d2, tot = t012 + d3;
            int inc = tot;
#pragma unroll
            for (int d = 1; d < 64; d <<= 1) {
                int o = __shfl_up(inc, d, 64);
                if (lane >= d) inc += o;
            }
            if (lane == 63) swar[wid] = inc;
            __syncthreads();
            if (wid == 0) {
                int v = (lane < 16) ? swar[lane] : 0;
                int vin = v;
#pragma unroll
                for (int d = 1; d < 16; d <<= 1) {
                    int o = __shfl_up(v, d, 64);
                    if (lane >= d) v += o;
                }
                if (lane < 16) swar[lane] = v - vin;
            }
            __syncthreads();
            int base = swar[wid] + (inc - tot);
            off[i0] = (u16)base;
            off[i0 + 1] = (u16)(base + t0);
            off[i0 + 2] = (u16)(base + t01);
            off[i0 + 3] = (u16)(base + t012);
        }
        __syncthreads();
        for (int e = tid; e < M2; e += 1024) {
            int i = e >> 1;
            u32 w = uvp[i];
            int src = (e & 1) ? (int)(w & 0xFFFF) : (int)(w >> 16);
            u32 old = atomicAdd((u32*)off + (src >> 1), 1u << ((src & 1) * 16));
            u32 slot = (old >> ((src & 1) * 16)) & 0xFFFFu;
            adj[slot] = (u16)e;
            succ[e] = (u16)slot;                 // temp: my slot
        }
        __syncthreads();
        const int e0 = adj[0];                   // first edge out of vertex 0 = tour start
        {
            u16 nsv[8];
            int k = 0;
            for (int e = tid; e < M2; e += 1024) {
                int i = e >> 1;
                u32 w = uvp[i];
                int v = (e & 1) ? (int)(w >> 16) : (int)(w & 0xFFFF);   // dst(e)
                int st = succ[e ^ 1];
                int start = (v == 0) ? 0 : off[v - 1];
                int end = off[v];
                int ns = (st + 1 < end) ? st + 1 : start;
                nsv[k++] = adj[ns];
            }
            __syncthreads();
            k = 0;
            for (int e = tid; e < M2; e += 1024) succ[e] = nsv[k++];
        }
        __syncthreads();
        for (int e = tid; e < M2; e += 1024) {
            u16 s = succ[e];
            if (s == (u16)e0) { succ[e] = (u16)e; rnk[e] = 0; }
            else rnk[e] = 1;
        }
        __syncthreads();
        for (int it = 0; it < 13; ++it) {
            u16 nr[8], s2[8];
            int k = 0;
            for (int e = tid; e < M2; e += 1024) {
                u16 s1 = succ[e];
                u16 r1 = rnk[e];
                nr[k] = (u16)(r1 + rnk[s1]);
                s2[k] = succ[s1];
                ++k;
            }
            __syncthreads();
            k = 0;
            for (int e = tid; e < M2; e += 1024) { rnk[e] = nr[k]; succ[e] = s2[k]; ++k; }
            __syncthreads();
        }
        for (int i = tid; i < N; i += 1024) minp[i] = 0xFFFFFFFFu;
        __syncthreads();
        for (int e = tid; e < M2; e += 1024) {
            int i = e >> 1;
            u32 w = uvp[i];
            int dst = (e & 1) ? (int)(w >> 16) : (int)(w & 0xFFFF);
            int srcv = (e & 1) ? (int)(w & 0xFFFF) : (int)(w >> 16);
            u32 p = (u32)(M2 - 1) - (u32)rnk[e];
            atomicMin(&minp[dst], (p << 16) | (u32)srcv);
        }
        __syncthreads();
        for (int v = tid; v < N; v += 1024) gpar[v] = (v == 0) ? 0 : (int)(minp[v] & 0xFFFFu);
    }

    // ---- global arrive; block 0 waits for all 64, then computes outputs ----
    __syncthreads();
    if (tid == 0) {
        __threadfence();
        atomicAdd(garr, 1);
    }
    if (b != 0) return;
    if (tid == 0) {
        while (__hip_atomic_load(garr, __ATOMIC_ACQUIRE, __HIP_MEMORY_SCOPE_AGENT) < 2 * MBLK)
            __builtin_amdgcn_s_sleep(1);
        __threadfence();
    }
    __syncthreads();

    // fused finalize (block 0 only)
    {
        float* rs12 = (float*)SM;            // tiny scratch
        float* rs21 = (float*)(SM + 64);
        int* rm = (int*)(SM + 128);
        const int* p1 = parent_g;
        const int* p2 = parent_g + N;
        float s12 = 0.f, s21 = 0.f;
        int mcnt = 0;
        for (int c = 1 + tid; c < N; c += 1024) {
            int a = p1[c];
            int bb = p2[c];
            float e1 = D1[(size_t)a * N + c] - D2[(size_t)a * N + c];
            float e2 = D2[(size_t)bb * N + c] - D1[(size_t)bb * N + c];
            s12 += e1 * e1;
            s21 += e2 * e2;
            mcnt += (a == bb) ? 1 : 0;
        }
#pragma unroll
        for (int off = 32; off > 0; off >>= 1) {
            s12 += __shfl_xor(s12, off, 64);
            s21 += __shfl_xor(s21, off, 64);
            mcnt += __shfl_xor(mcnt, off, 64);
        }
        if (lane == 0) { rs12[wid] = s12; rs21[wid] = s21; rm[wid] = mcnt; }
        __syncthreads();
        if (tid == 0) {
            float a = 0.f, bb = 0.f;
            int mm = 0;
#pragma unroll
            for (int w = 0; w < 16; ++w) { a += rs12[w]; bb += rs21[w]; mm += rm[w]; }
            float d12 = sqrtf(a);
            float d21 = sqrtf(bb);
            out[0] = d12 + d21;
            out[1] = d12;
            out[2] = d21;
            out[3] = (float)mm;
        }
    }
}

extern "C" void kernel_launch(void* const* d_in, const int* in_sizes, int n_in,
                              void* d_out, int out_size, void* d_ws, size_t ws_size,
                              hipStream_t stream) {
    const float* D1 = (const float*)d_in[0];
    const float* D2 = (const float*)d_in[1];

    int* parent = WS_PARENT(d_ws);
    int* rcnt = WS_RCNT(d_ws);
    float* rthr = WS_RTHR(d_ws);
    int2* edges = WS_EDGES(d_ws);
    u64* cand = WS_CAND(d_ws);
    int* meta = WS_META(d_ws);
    u64* lists = WS_LISTS(d_ws);

    build_kernel<<<512, 1024, 0, stream>>>(D1, D2, rcnt, rthr, lists, cand, meta);
    solve_kernel<<<2 * MBLK, 1024, 0, stream>>>(D1, D2, rcnt, rthr, lists, cand,
                                                edges, parent, meta, (float*)d_out);
}